// Round 8
// baseline (2584.255 us; speedup 1.0000x reference)
//
#include <hip/hip_runtime.h>
#include <math.h>

#define FLAG_ACC     1
#define FLAG_RELU    2
#define FLAG_GELU    4
#define FLAG_ABF16   8
#define FLAG_OBF16  16
#define FLAG_RESB16 32

typedef __attribute__((ext_vector_type(8))) short short8;
typedef __attribute__((ext_vector_type(4))) short short4v;
typedef __attribute__((ext_vector_type(4))) float f32x4;

__device__ __forceinline__ short f2bf(float f) {
  unsigned u = __builtin_bit_cast(unsigned, f);
  unsigned r = u + 0x7fffu + ((u >> 16) & 1u);
  return (short)(r >> 16);
}
__device__ __forceinline__ float bf2f(short s) {
  unsigned u = ((unsigned)(unsigned short)s) << 16;
  return __builtin_bit_cast(float, u);
}
__device__ __forceinline__ void load_lds16(const void* g, void* lds) {
  __builtin_amdgcn_global_load_lds(
      (const __attribute__((address_space(1))) void*)g,
      (__attribute__((address_space(3))) void*)lds, 16, 0, 0);
}

// ---------------- generic fp32 tiled GEMM (head + W_vo prep) ----------------
__global__ __launch_bounds__(256) void gemm_f32(
    const float* __restrict__ A, const float* __restrict__ B, float* __restrict__ C,
    int M, int N, int K, int a_shift,
    const float* __restrict__ bias, const float* __restrict__ residual, int flags)
{
  __shared__ float As[16][65];
  __shared__ float Bs[16][64];
  const int tid = threadIdx.x;
  const int tx = tid & 15, ty = tid >> 4;
  const int row0 = blockIdx.y * 64;
  const int col0 = blockIdx.x * 64;
  int kbeg = 0, kend = K;
  if ((int)gridDim.z > 1) {
    int kchunk = ((K + (int)gridDim.z - 1) / (int)gridDim.z + 15) & ~15;
    kbeg = (int)blockIdx.z * kchunk;
    kend = min(K, kbeg + kchunk);
  }
  float acc[4][4] = {};
  const int a_m = tid >> 2;
  const int a_k = (tid & 3) << 2;
  const int b_n = (tid & 15) << 2;
  const int b_k = tid >> 4;
  for (int k0 = kbeg; k0 < kend; k0 += 16) {
    int srow = row0 + a_m + a_shift;
    float4 av = make_float4(0.f, 0.f, 0.f, 0.f);
    if (srow >= 0 && srow < M)
      av = *reinterpret_cast<const float4*>(A + (long long)srow * K + (k0 + a_k));
    As[a_k + 0][a_m] = av.x; As[a_k + 1][a_m] = av.y;
    As[a_k + 2][a_m] = av.z; As[a_k + 3][a_m] = av.w;
    float4 bv = make_float4(0.f, 0.f, 0.f, 0.f);
    int brow = k0 + b_k;
    if (brow < K)
      bv = *reinterpret_cast<const float4*>(B + (long long)brow * N + (col0 + b_n));
    Bs[b_k][b_n + 0] = bv.x; Bs[b_k][b_n + 1] = bv.y;
    Bs[b_k][b_n + 2] = bv.z; Bs[b_k][b_n + 3] = bv.w;
    __syncthreads();
#pragma unroll
    for (int kk = 0; kk < 16; kk++) {
      float ar[4], br[4];
#pragma unroll
      for (int i = 0; i < 4; i++) ar[i] = As[kk][ty * 4 + i];
#pragma unroll
      for (int j = 0; j < 4; j++) br[j] = Bs[kk][tx * 4 + j];
#pragma unroll
      for (int i = 0; i < 4; i++)
#pragma unroll
        for (int j = 0; j < 4; j++)
          acc[i][j] += ar[i] * br[j];
    }
    __syncthreads();
  }
  if ((int)gridDim.z > 1) {
#pragma unroll
    for (int i = 0; i < 4; i++) {
      int r = row0 + ty * 4 + i; if (r >= M) continue;
#pragma unroll
      for (int j = 0; j < 4; j++) {
        int c = col0 + tx * 4 + j; if (c >= N) continue;
        atomicAdd(&C[(long long)r * N + c], acc[i][j]);
      }
    }
    return;
  }
#pragma unroll
  for (int i = 0; i < 4; i++) {
    int r = row0 + ty * 4 + i; if (r >= M) continue;
#pragma unroll
    for (int j = 0; j < 4; j++) {
      int c = col0 + tx * 4 + j; if (c >= N) continue;
      float v = acc[i][j];
      if (bias)     v += bias[c];
      if (residual) v += residual[(long long)r * N + c];
      if (flags & FLAG_ACC)  v += C[(long long)r * N + c];
      if (flags & FLAG_RELU) v = fmaxf(v, 0.f);
      if (flags & FLAG_GELU) v = 0.5f * v * (1.f + erff(v * 0.70710678118654752f));
      C[(long long)r * N + c] = v;
    }
  }
}

// ---------------- bf16 MFMA GEMM, BK=64, N-tile = 128*NT -------------------------
// R2 single-buffered structure (measured best). NT widens per-block column
// coverage: halves the A-panel re-reads from L2/L3 (the measured limiter --
// time invariant to k-loop scheduling, FETCH hidden by cache).
// grid = (M/128, N/(128*NT)).
template<int NT>
__global__ __launch_bounds__(256) void gemm_btn(
    const void* __restrict__ Av, const short* __restrict__ Btb, void* __restrict__ Cv,
    const float* __restrict__ residual, const float* __restrict__ bias,
    int M, int N, int K, int lda, int flags, int tapped)
{
  __shared__ __align__(16) short Asl[8192];
  __shared__ __align__(16) short Bsl[NT * 8192];
  const int tid = threadIdx.x;
  const int row0 = blockIdx.x * 128;
  const int col0 = blockIdx.y * (128 * NT);
  const int lane = tid & 63;
  const int wave = tid >> 6;
  const int wm = (wave >> 1) * 64;
  const int wn = (wave & 1) * 64;
  const int fm = lane & 15;
  const int k8c = lane >> 4;
  const int mr = tid >> 1;
  const int mkc = (tid & 1) * 4;
  const int msw = mr & 7;
  const bool a_dma = (flags & FLAG_ABF16) && !tapped;

  f32x4 acc[4][4 * NT] = {};
  for (int k0 = 0; k0 < K; k0 += 64) {
    __syncthreads();
#pragma unroll
    for (int t = 0; t < NT; t++)
#pragma unroll
      for (int u = 0; u < 4; u++) {          // B via DMA, NT tiles
        int p = (wave * 4 + u) * 64 + lane;
        int r = p >> 3;
        int kc = (p & 7) ^ (r & 7);
        load_lds16(Btb + (long long)(col0 + t * 128 + r) * K + k0 + kc * 8,
                   (char*)Bsl + t * 16384 + (wave * 4 + u) * 1024);
      }
    if (a_dma) {
      const short* Ab = (const short*)Av;
#pragma unroll
      for (int u = 0; u < 4; u++) {
        int p = (wave * 4 + u) * 64 + lane;
        int r = p >> 3;
        int kc = (p & 7) ^ (r & 7);
        load_lds16(Ab + (long long)(row0 + r) * lda + k0 + kc * 8,
                   (char*)Asl + (wave * 4 + u) * 1024);
      }
    } else {
      int arow = row0 + mr + (tapped ? (k0 >> 8) - 1 : 0);
      int acol = tapped ? (k0 & 255) : k0;
      bool ok = (arow >= 0 && arow < M);
      if (flags & FLAG_ABF16) {
        const short* ga = (const short*)Av + (long long)arow * lda + acol + mkc * 8;
        short8 z;
#pragma unroll
        for (int u = 0; u < 8; u++) z[u] = 0;
#pragma unroll
        for (int j = 0; j < 4; j++) {
          short8 v = ok ? *(const short8*)(ga + j * 8) : z;
          *(short8*)&Asl[(mr * 8 + ((mkc + j) ^ msw)) * 8] = v;
        }
      } else {
        const float* ga = (const float*)Av + (long long)arow * lda + acol + mkc * 8;
#pragma unroll
        for (int j = 0; j < 4; j++) {
          float4 f0 = make_float4(0.f,0.f,0.f,0.f), f1 = f0;
          if (ok) { f0 = *(const float4*)(ga + j * 8); f1 = *(const float4*)(ga + j * 8 + 4); }
          short8 v;
          v[0]=f2bf(f0.x); v[1]=f2bf(f0.y); v[2]=f2bf(f0.z); v[3]=f2bf(f0.w);
          v[4]=f2bf(f1.x); v[5]=f2bf(f1.y); v[6]=f2bf(f1.z); v[7]=f2bf(f1.w);
          *(short8*)&Asl[(mr * 8 + ((mkc + j) ^ msw)) * 8] = v;
        }
      }
    }
    __syncthreads();
#pragma unroll
    for (int kk8 = 0; kk8 < 8; kk8 += 4) {
      short8 af[4];
#pragma unroll
      for (int i = 0; i < 4; i++) {
        int r = wm + i * 16 + fm;
        af[i] = *(short8*)&Asl[(r * 8 + ((kk8 + k8c) ^ (r & 7))) * 8];
      }
#pragma unroll
      for (int t = 0; t < NT; t++) {
        short8 bf[4];
#pragma unroll
        for (int j = 0; j < 4; j++) {
          int r = wn + j * 16 + fm;
          bf[j] = *(short8*)&Bsl[t * 8192 + (r * 8 + ((kk8 + k8c) ^ (r & 7))) * 8];
        }
#pragma unroll
        for (int i = 0; i < 4; i++)
#pragma unroll
          for (int j = 0; j < 4; j++)
            acc[i][t * 4 + j] = __builtin_amdgcn_mfma_f32_16x16x32_bf16(
                af[i], bf[j], acc[i][t * 4 + j], 0, 0, 0);
      }
    }
  }
#pragma unroll
  for (int t = 0; t < NT; t++)
#pragma unroll
  for (int i = 0; i < 4; i++) {
    const int mbase = row0 + wm + i * 16 + (lane >> 4) * 4;
#pragma unroll
    for (int j = 0; j < 4; j++) {
      const int n = col0 + t * 128 + wn + j * 16 + fm;
      const float bs = bias ? bias[n] : 0.f;
#pragma unroll
      for (int r = 0; r < 4; r++) {
        long long idx = (long long)(mbase + r) * N + n;
        float v = acc[i][t * 4 + j][r] + bs;
        if (residual) {
          if (flags & FLAG_RESB16) v += bf2f(((const short*)residual)[idx]);
          else                     v += residual[idx];
        }
        if (flags & FLAG_ACC)  v += ((const float*)Cv)[idx];
        if (flags & FLAG_RELU) v = fmaxf(v, 0.f);
        if (flags & FLAG_GELU) v = 0.5f * v * (1.f + erff(v * 0.70710678118654752f));
        if (flags & FLAG_OBF16) ((short*)Cv)[idx] = f2bf(v);
        else                    ((float*)Cv)[idx] = v;
      }
    }
  }
}

// ---------------- q+k GEMM with fp32 TRANSPOSED output QT[b][c][t] -----------------
// A single bf16 (DMA), B pre-split h/l (DMA), 2 MFMAs, epilogue writes QT fp32.
// QT layout: [(b*512 + n) * 1024 + l]   (n<256: q channel, n>=256: k channel)
__global__ __launch_bounds__(256) void gemm_qkT(
    const short* __restrict__ Ab, const short* __restrict__ Bth,
    const short* __restrict__ Btl, float* __restrict__ QT,
    const float* __restrict__ bias, int K)
{
  __shared__ __align__(16) char smem[24576];
  short* Asl = (short*)smem;
  short* Bhi = (short*)(smem + 8192);
  short* Blo = (short*)(smem + 16384);
  const int tid = threadIdx.x;
  const int row0 = blockIdx.x * 128;
  const int col0 = blockIdx.y * 128;
  const int lane = tid & 63;
  const int wave = tid >> 6;
  const int wm = (wave >> 1) * 64;
  const int wn = (wave & 1) * 64;
  const int fm = lane & 15;
  const int k8c = lane >> 4;

  f32x4 acc[4][4] = {};
  for (int k0 = 0; k0 < K; k0 += 32) {
    __syncthreads();
#pragma unroll
    for (int u = 0; u < 2; u++) {
      int p = (wave + u * 4) * 64 + lane;
      int r = p >> 2;
      int kc = (p & 3) ^ ((r >> 1) & 3);
      long long ao = (long long)(row0 + r) * 256 + k0 + kc * 8;
      long long go = (long long)(col0 + r) * K + k0 + kc * 8;
      int lo = (wave + u * 4) * 1024;
      load_lds16(Ab + ao, (char*)Asl + lo);
      load_lds16(Bth + go, (char*)Bhi + lo);
      load_lds16(Btl + go, (char*)Blo + lo);
    }
    __syncthreads();
    short8 af[4], bh[4], bl[4];
#pragma unroll
    for (int i = 0; i < 4; i++) {
      int r = wm + i * 16 + fm;
      af[i] = *(short8*)&Asl[(r * 4 + (k8c ^ ((r >> 1) & 3))) * 8];
    }
#pragma unroll
    for (int j = 0; j < 4; j++) {
      int r = wn + j * 16 + fm;
      int p = (r * 4 + (k8c ^ ((r >> 1) & 3))) * 8;
      bh[j] = *(short8*)&Bhi[p];
      bl[j] = *(short8*)&Blo[p];
    }
#pragma unroll
    for (int i = 0; i < 4; i++)
#pragma unroll
      for (int j = 0; j < 4; j++) {
        acc[i][j] = __builtin_amdgcn_mfma_f32_16x16x32_bf16(af[i], bh[j], acc[i][j], 0, 0, 0);
        acc[i][j] = __builtin_amdgcn_mfma_f32_16x16x32_bf16(af[i], bl[j], acc[i][j], 0, 0, 0);
      }
  }
#pragma unroll
  for (int i = 0; i < 4; i++) {
    const int mbase = row0 + wm + i * 16 + (lane >> 4) * 4;
    const int bb = mbase >> 10;
    const int l  = mbase & 1023;
#pragma unroll
    for (int j = 0; j < 4; j++) {
      const int n = col0 + wn + j * 16 + fm;
      const float bs = bias[n];
      float4 o = make_float4(acc[i][j][0] + bs, acc[i][j][1] + bs,
                             acc[i][j][2] + bs, acc[i][j][3] + bs);
      *(float4*)&QT[((long long)(bb * 512 + n) << 10) + l] = o;
    }
  }
}

// ---------------- FFT-based autocorrelation mean -----------------------------------
#define SKW(i) ((i) + ((i) >> 5))

__device__ __forceinline__ int rev4_10(int f) {
  return ((f & 3) << 8) | (((f >> 2) & 3) << 6) | (((f >> 4) & 3) << 4)
       | (((f >> 6) & 3) << 2) | ((f >> 8) & 3);
}

template<int M, bool INV, int NCH>
__device__ __forceinline__ void fft_stageN(float2 (*__restrict__ buf)[1056],
                                           const float2* __restrict__ tw, int t) {
  constexpr int LOG2M = (M == 256) ? 8 : (M == 64) ? 6 : (M == 16) ? 4 : (M == 4) ? 2 : 0;
  const int j = t & (M - 1);
  const int base = ((t >> LOG2M) << (LOG2M + 2)) | j;
  float2 w = tw[SKW(j << (8 - LOG2M))];
  const float c1 = w.x, s1 = INV ? -w.y : w.y;
  const float c2 = c1 * c1 - s1 * s1, s2 = 2.f * c1 * s1;
  const float c3 = c2 * c1 - s2 * s1, s3 = c2 * s1 + s2 * c1;
#pragma unroll
  for (int ch = 0; ch < NCH; ch++) {
    float2* s = buf[ch];
    float2 a0 = s[SKW(base)];
    float2 b0 = s[SKW(base + M)];
    float2 d0 = s[SKW(base + 2 * M)];
    float2 e0 = s[SKW(base + 3 * M)];
    float t0r = a0.x + d0.x, t0i = a0.y + d0.y;
    float t1r = a0.x - d0.x, t1i = a0.y - d0.y;
    float t2r = b0.x + e0.x, t2i = b0.y + e0.y;
    float t3r = b0.x - e0.x, t3i = b0.y - e0.y;
    float y0r = t0r + t2r, y0i = t0i + t2i;
    float y2r = t0r - t2r, y2i = t0i - t2i;
    float y1r, y1i, y3r, y3i;
    if (!INV) { y1r = t1r + t3i; y1i = t1i - t3r; y3r = t1r - t3i; y3i = t1i + t3r; }
    else      { y1r = t1r - t3i; y1i = t1i + t3r; y3r = t1r + t3i; y3i = t1i - t3r; }
    s[SKW(base)]         = make_float2(y0r, y0i);
    s[SKW(base + M)]     = make_float2(y1r * c1 - y1i * s1, y1r * s1 + y1i * c1);
    s[SKW(base + 2 * M)] = make_float2(y2r * c2 - y2i * s2, y2r * s2 + y2i * c2);
    s[SKW(base + 3 * M)] = make_float2(y3r * c3 - y3i * s3, y3r * s3 + y3i * c3);
  }
}

__global__ __launch_bounds__(256) void fft_cross(
    const float* __restrict__ QT, float* __restrict__ Rpart)
{
  __shared__ float2 buf[4][1056];
  __shared__ float2 tw[264];
  const int tid = threadIdx.x;
  const int b = blockIdx.x & 63;
  const int g = blockIdx.x >> 6;
  {
    float s, c;
    sincosf(-1.5707963267948966f * (float)tid * (1.f / 256.f), &s, &c);
    tw[SKW(tid)] = make_float2(c, s);
  }
  const float* Qb = QT + (long long)b * 524288;
  const int c0 = g * 16;
  float4 qv[4], kv[4];
#pragma unroll
  for (int c = 0; c < 4; c++) {
    qv[c] = *(const float4*)(Qb + ((long long)(c0 + c) << 10) + tid * 4);
    kv[c] = *(const float4*)(Qb + ((long long)(256 + c0 + c) << 10) + tid * 4);
  }
  float aR[4] = {0.f, 0.f, 0.f, 0.f}, aI[4] = {0.f, 0.f, 0.f, 0.f};
  __syncthreads();
  for (int q4 = 0; q4 < 4; q4++) {
    const int i0 = tid * 4;
#pragma unroll
    for (int c = 0; c < 4; c++) {
      buf[c][SKW(i0 + 0)] = make_float2(qv[c].x, kv[c].x);
      buf[c][SKW(i0 + 1)] = make_float2(qv[c].y, kv[c].y);
      buf[c][SKW(i0 + 2)] = make_float2(qv[c].z, kv[c].z);
      buf[c][SKW(i0 + 3)] = make_float2(qv[c].w, kv[c].w);
    }
    if (q4 < 3) {
      const int cb = c0 + (q4 + 1) * 4;
#pragma unroll
      for (int c = 0; c < 4; c++) {
        qv[c] = *(const float4*)(Qb + ((long long)(cb + c) << 10) + tid * 4);
        kv[c] = *(const float4*)(Qb + ((long long)(256 + cb + c) << 10) + tid * 4);
      }
    }
    __syncthreads();
    fft_stageN<256, false, 4>(buf, tw, tid); __syncthreads();
    fft_stageN<64,  false, 4>(buf, tw, tid); __syncthreads();
    fft_stageN<16,  false, 4>(buf, tw, tid); __syncthreads();
    fft_stageN<4,   false, 4>(buf, tw, tid); __syncthreads();
    fft_stageN<1,   false, 4>(buf, tw, tid); __syncthreads();
#pragma unroll
    for (int u = 0; u < 4; u++) {
      const int f = tid + (u << 8);
      const int p1 = SKW(rev4_10(f));
      const int p2 = SKW(rev4_10((1024 - f) & 1023));
#pragma unroll
      for (int c = 0; c < 4; c++) {
        float2 z1 = buf[c][p1];
        float2 z2 = buf[c][p2];
        float Qr = 0.5f * (z1.x + z2.x), Qi = 0.5f * (z1.y - z2.y);
        float Kr = 0.5f * (z1.y + z2.y), Ki = 0.5f * (z2.x - z1.x);
        aR[u] += Qr * Kr + Qi * Ki;
        aI[u] += Qi * Kr - Qr * Ki;
      }
    }
    __syncthreads();
  }
  float* Rp = Rpart + (long long)(g * 64 + b) * 2048;
#pragma unroll
  for (int u = 0; u < 4; u++) {
    Rp[tid + (u << 8)] = aR[u];
    Rp[1024 + tid + (u << 8)] = aI[u];
  }
}

__global__ __launch_bounds__(256) void fft_inv(
    const float* __restrict__ Rpart, float* __restrict__ MV)
{
  __shared__ float2 ping[1056], tw[264];
  const int tid = threadIdx.x;
  const int b = blockIdx.x;
  {
    float s, c;
    sincosf(-1.5707963267948966f * (float)tid * (1.f / 256.f), &s, &c);
    tw[SKW(tid)] = make_float2(c, s);
  }
#pragma unroll
  for (int u = 0; u < 4; u++) {
    int f = tid + (u << 8);
    float sr = 0.f, si = 0.f;
#pragma unroll
    for (int g = 0; g < 16; g++) {
      const float* Rp = Rpart + (long long)(g * 64 + b) * 2048;
      sr += Rp[f];
      si += Rp[1024 + f];
    }
    ping[SKW(f)] = make_float2(sr, si);
  }
  __syncthreads();
  float2 (*bp)[1056] = reinterpret_cast<float2 (*)[1056]>(ping);
  fft_stageN<256, true, 1>(bp, tw, tid); __syncthreads();
  fft_stageN<64,  true, 1>(bp, tw, tid); __syncthreads();
  fft_stageN<16,  true, 1>(bp, tw, tid); __syncthreads();
  fft_stageN<4,   true, 1>(bp, tw, tid); __syncthreads();
  fft_stageN<1,   true, 1>(bp, tw, tid); __syncthreads();
  const float sc = 1.f / (1024.f * 256.f);
#pragma unroll
  for (int u = 0; u < 4; u++) {
    int p = tid + (u << 8);
    MV[(long long)b * 1024 + rev4_10(p)] = ping[SKW(p)].x * sc;
  }
}

// ------------- one-shot weight prep -------------
__global__ void prep_weights(
    const float* __restrict__ conv2_w, const float* __restrict__ Wq,
    const float* __restrict__ Wk, const float* __restrict__ Wff1,
    const float* __restrict__ Wff2,
    const float* __restrict__ bq, const float* __restrict__ bk,
    short* __restrict__ CB2Tb, short* __restrict__ QKTH, short* __restrict__ QKTL,
    short* __restrict__ WFF1b, short* __restrict__ WFF2b, float* __restrict__ BQK)
{
  const int total = 196608 + 262144 + 524288 + 524288 + 1024;
  for (int idx = blockIdx.x * 256 + threadIdx.x; idx < total;
       idx += gridDim.x * 256) {
    int t = idx;
    if (t < 196608) {
      int o = t / 768, rem = t % 768, kk = rem >> 8, i = rem & 255;
      CB2Tb[t] = f2bf(conv2_w[(o * 256 + i) * 3 + kk]);
    } else if ((t -= 196608) < 262144) {
      int L = t >> 17, rem = t & 131071, r = rem >> 8, k = rem & 255;
      float val = (r < 256) ? Wq[L * 65536 + k * 256 + r]
                            : Wk[L * 65536 + k * 256 + (r - 256)];
      short h = f2bf(val);
      QKTH[t] = h;
      QKTL[t] = f2bf(val - bf2f(h));
    } else if ((t -= 262144) < 524288) {
      WFF1b[t] = f2bf(Wff1[t]);
    } else if ((t -= 524288) < 524288) {
      WFF2b[t] = f2bf(Wff2[t]);
    } else {
      t -= 524288;
      int L = t >> 9, j = t & 511;
      BQK[t] = (j < 256) ? bq[L * 256 + j] : bk[L * 256 + (j - 256)];
    }
  }
}

// ------------- W_vo finish -------------
__global__ void vo_finish(const float* __restrict__ WVO, const float* __restrict__ Wo,
                          const float* __restrict__ bv, const float* __restrict__ bo,
                          short* __restrict__ WVOTb, float* __restrict__ BVO)
{
  const int total = 131072 + 512;
  for (int idx = blockIdx.x * 256 + threadIdx.x; idx < total;
       idx += gridDim.x * 256) {
    if (idx < 131072) {
      int L = idx >> 16, rem = idx & 65535, n = rem >> 8, k = rem & 255;
      WVOTb[idx] = f2bf(WVO[L * 65536 + k * 256 + n]);
    } else {
      int j = idx - 131072;
      int L = j >> 8, n = j & 255;
      float acc = bo[L * 256 + n];
      for (int k = 0; k < 256; k++)
        acc += bv[L * 256 + k] * Wo[(long long)L * 65536 + k * 256 + n];
      BVO[j] = acc;
    }
  }
}

// ------------- conv1 direct -> bf16 out -------------
__global__ __launch_bounds__(256) void conv1_direct(
    const float* __restrict__ x, const float* __restrict__ w,
    const float* __restrict__ bias, short* __restrict__ out)
{
  __shared__ float xs[66][16];
  const int b = blockIdx.y, lg = blockIdx.x, tid = threadIdx.x;
  const int l0 = lg * 64;
  for (int idx = tid; idx < 1056; idx += 256) {
    int r = idx >> 4, c = idx & 15;
    int l = l0 + r - 1;
    xs[r][c] = (l >= 0 && l < 1024) ? x[((long long)b * 1024 + l) * 16 + c] : 0.f;
  }
  float wr[48];
#pragma unroll
  for (int u = 0; u < 48; u++) wr[u] = w[tid * 48 + u];
  const float bs = bias[tid];
  __syncthreads();
  for (int r = 0; r < 64; r++) {
    float acc = bs;
#pragma unroll
    for (int i = 0; i < 16; i++) {
      acc += xs[r + 0][i] * wr[i * 3 + 0];
      acc += xs[r + 1][i] * wr[i * 3 + 1];
      acc += xs[r + 2][i] * wr[i * 3 + 2];
    }
    out[((long long)b * 1024 + l0 + r) * 256 + tid] = f2bf(fmaxf(acc, 0.f));
  }
}

// ------------- conv2 batch-edge fixup (bf16 src rows, bf16 out) -------------
__global__ void fixup_conv_b(short* __restrict__ h, const short* __restrict__ src,
                             const float* __restrict__ w, const float* __restrict__ bias)
{
  int b = blockIdx.x >> 1;
  int l = (blockIdx.x & 1) ? 1023 : 0;
  int o = threadIdx.x;
  float acc = bias[o];
  for (int kk = 0; kk < 3; kk++) {
    int t = l + kk - 1;
    if (t < 0 || t > 1023) continue;
    const short* srow = src + ((long long)b * 1024 + t) * 256;
    const float* wrow = w + (long long)o * 256 * 3 + kk;
    for (int i = 0; i < 256; i++) acc += bf2f(srow[i]) * wrow[(long long)i * 3];
  }
  h[((long long)b * 1024 + l) * 256 + o] = f2bf(fmaxf(acc, 0.f));
}

// ------------- LayerNorm fp32 out (head path) -------------
__global__ __launch_bounds__(256) void ln_rows4(
    const float* __restrict__ in, float* __restrict__ out,
    const float* __restrict__ g, const float* __restrict__ b,
    int prerelu, int out_stride, int out_off)
{
  const int row = blockIdx.x * 4 + (threadIdx.x >> 6);
  const int lane = threadIdx.x & 63;
  float4 x = ((const float4*)(in + (long long)row * 256))[lane];
  if (prerelu) {
    x.x = fmaxf(x.x, 0.f); x.y = fmaxf(x.y, 0.f);
    x.z = fmaxf(x.z, 0.f); x.w = fmaxf(x.w, 0.f);
  }
  float s = x.x + x.y + x.z + x.w;
#pragma unroll
  for (int o = 32; o > 0; o >>= 1) s += __shfl_xor(s, o, 64);
  float mean = s * (1.f / 256.f);
  float4 d = make_float4(x.x - mean, x.y - mean, x.z - mean, x.w - mean);
  float s2 = d.x * d.x + d.y * d.y + d.z * d.z + d.w * d.w;
#pragma unroll
  for (int o = 32; o > 0; o >>= 1) s2 += __shfl_xor(s2, o, 64);
  float rsd = rsqrtf(s2 * (1.f / 256.f) + 1e-5f);
  float4 gg = ((const float4*)g)[lane];
  float4 bb = ((const float4*)b)[lane];
  float4 o4 = make_float4(d.x * rsd * gg.x + bb.x, d.y * rsd * gg.y + bb.y,
                          d.z * rsd * gg.z + bb.z, d.w * rsd * gg.w + bb.w);
  ((float4*)(out + (long long)row * out_stride + out_off))[lane] = o4;
}

// ------------- LayerNorm bf16 in -> bf16 out (enc producer) -------------
__global__ __launch_bounds__(256) void ln_rows4bb(
    const short* __restrict__ in, short* __restrict__ out,
    const float* __restrict__ g, const float* __restrict__ b)
{
  const int row = blockIdx.x * 4 + (threadIdx.x >> 6);
  const int lane = threadIdx.x & 63;
  short4v xb = ((const short4v*)in)[(long long)row * 64 + lane];
  float4 x = make_float4(bf2f(xb[0]), bf2f(xb[1]), bf2f(xb[2]), bf2f(xb[3]));
  float s = x.x + x.y + x.z + x.w;
#pragma unroll
  for (int o = 32; o > 0; o >>= 1) s += __shfl_xor(s, o, 64);
  float mean = s * (1.f / 256.f);
  float4 d = make_float4(x.x - mean, x.y - mean, x.z - mean, x.w - mean);
  float s2 = d.x * d.x + d.y * d.y + d.z * d.z + d.w * d.w;
#pragma unroll
  for (int o = 32; o > 0; o >>= 1) s2 += __shfl_xor(s2, o, 64);
  float rsd = rsqrtf(s2 * (1.f / 256.f) + 1e-5f);
  float4 gg = ((const float4*)g)[lane];
  float4 bb = ((const float4*)b)[lane];
  short4v o4;
  o4[0] = f2bf(d.x * rsd * gg.x + bb.x);
  o4[1] = f2bf(d.y * rsd * gg.y + bb.y);
  o4[2] = f2bf(d.z * rsd * gg.z + bb.z);
  o4[3] = f2bf(d.w * rsd * gg.w + bb.w);
  ((short4v*)out)[(long long)row * 64 + lane] = o4;
}

// ------------- series_decomp bf16 -> bf16 enc (+fp32 FIN pool row), XCD-clustered --
__global__ void decomp4bf(const short* __restrict__ in, short* __restrict__ out,
                          float* __restrict__ fin, int finoff)
{
  const int id = blockIdx.x;
  const int c = id & 7;
  const int s = id >> 3;
  const int b = c + 8 * (s >> 8);
  const int lg = s & 255;
  const int l = lg * 4 + (threadIdx.x >> 6);
  const int c4 = threadIdx.x & 63;
  const short4v* base = (const short4v*)(in + (long long)b * 262144);
  float4 acc = make_float4(0.f, 0.f, 0.f, 0.f);
#pragma unroll
  for (int j = -12; j <= 12; j++) {
    int t = l + j;
    t = t < 0 ? 0 : (t > 1023 ? 1023 : t);
    short4v x = base[t * 64 + c4];
    acc.x += bf2f(x[0]); acc.y += bf2f(x[1]);
    acc.z += bf2f(x[2]); acc.w += bf2f(x[3]);
  }
  short4v x0 = base[l * 64 + c4];
  float4 o = make_float4(bf2f(x0[0]) - acc.x * (1.f / 25.f),
                         bf2f(x0[1]) - acc.y * (1.f / 25.f),
                         bf2f(x0[2]) - acc.z * (1.f / 25.f),
                         bf2f(x0[3]) - acc.w * (1.f / 25.f));
  short4v ob;
  ob[0] = f2bf(o.x); ob[1] = f2bf(o.y); ob[2] = f2bf(o.z); ob[3] = f2bf(o.w);
  ((short4v*)out)[((long long)b * 1024 + l) * 64 + c4] = ob;
  if (l == 1023) {
    float* f = fin + (long long)b * 768 + finoff + c4 * 4;
    f[0] = o.x; f[1] = o.y; f[2] = o.z; f[3] = o.w;
  }
}

// ------------- series_decomp bf16->bf16, XCD-clustered -------------
__global__ void decomp4b(const short* __restrict__ in, short* __restrict__ out)
{
  const int id = blockIdx.x;
  const int c = id & 7;
  const int s = id >> 3;
  const int b = c + 8 * (s >> 8);
  const int lg = s & 255;
  const int l = lg * 4 + (threadIdx.x >> 6);
  const int c4 = threadIdx.x & 63;
  const short4v* base = (const short4v*)(in + (long long)b * 262144);
  float4 acc = make_float4(0.f, 0.f, 0.f, 0.f);
#pragma unroll
  for (int j = -12; j <= 12; j++) {
    int t = l + j;
    t = t < 0 ? 0 : (t > 1023 ? 1023 : t);
    short4v x = base[t * 64 + c4];
    acc.x += bf2f(x[0]); acc.y += bf2f(x[1]);
    acc.z += bf2f(x[2]); acc.w += bf2f(x[3]);
  }
  short4v x0 = base[l * 64 + c4];
  short4v o;
  o[0] = f2bf(bf2f(x0[0]) - acc.x * (1.f / 25.f));
  o[1] = f2bf(bf2f(x0[1]) - acc.y * (1.f / 25.f));
  o[2] = f2bf(bf2f(x0[2]) - acc.z * (1.f / 25.f));
  o[3] = f2bf(bf2f(x0[3]) - acc.w * (1.f / 25.f));
  ((short4v*)(out + (long long)b * 262144))[l * 64 + c4] = o;
}

// ------------- top-20 + softmax, one wave per batch -------------
__global__ __launch_bounds__(64) void topk_softmax_wave(
    const float* __restrict__ mv, float* __restrict__ wts, int* __restrict__ dly)
{
  const int b = blockIdx.x, lane = threadIdx.x;
  float v[16];
#pragma unroll
  for (int j = 0; j < 16; j++)
    v[j] = mv[(long long)b * 1024 + lane + 64 * j];
  float selv = 0.f; int seli = 0;
  for (int it = 0; it < 20; it++) {
    float bv = -1e30f; int bi = 0x7fffffff;
#pragma unroll
    for (int j = 0; j < 16; j++) {
      float x = v[j]; int idx = lane + 64 * j;
      if (x > bv || (x == bv && idx < bi)) { bv = x; bi = idx; }
    }
#pragma unroll
    for (int off = 32; off > 0; off >>= 1) {
      float ov = __shfl_xor(bv, off, 64);
      int   oi = __shfl_xor(bi, off, 64);
      if (ov > bv || (ov == bv && oi < bi)) { bv = ov; bi = oi; }
    }
    if (lane == it) { selv = bv; seli = bi; }
    if ((bi & 63) == lane) v[bi >> 6] = -1e30f;
  }
  const float w0 = __shfl(selv, 0, 64);
  float e = (lane < 20) ? __expf(selv - w0) : 0.f;
  float s = e;
#pragma unroll
  for (int off = 32; off > 0; off >>= 1) s += __shfl_xor(s, off, 64);
  if (lane < 20) {
    wts[b * 20 + lane] = e / s;
    dly[b * 20 + lane] = seli;
  }
}

// ------------- delay aggregation bf16 enc -> bf16 out, XCD-clustered ---------------
__global__ void agg4b(const short* __restrict__ enc, const float* __restrict__ wts,
                      const int* __restrict__ dly, short* __restrict__ out)
{
  const int id = blockIdx.x;
  const int c = id & 7;
  const int s = id >> 3;
  const int b = c + 8 * (s >> 8);
  const int lg = s & 255;
  const int l = lg * 4 + (threadIdx.x >> 6);
  const int c4 = threadIdx.x & 63;
  const short4v* vb = (const short4v*)(enc + (long long)b * 262144);
  float4 acc = make_float4(0.f, 0.f, 0.f, 0.f);
  for (int kk = 0; kk < 20; kk++) {
    int d = dly[b * 20 + kk];
    float w = wts[b * 20 + kk];
    short4v x = vb[((l + d) & 1023) * 64 + c4];
    acc.x += w * bf2f(x[0]); acc.y += w * bf2f(x[1]);
    acc.z += w * bf2f(x[2]); acc.w += w * bf2f(x[3]);
  }
  short4v o;
  o[0] = f2bf(acc.x); o[1] = f2bf(acc.y); o[2] = f2bf(acc.z); o[3] = f2bf(acc.w);
  ((short4v*)(out + (long long)b * 262144))[l * 64 + c4] = o;
}

// ------------- small helpers -------------
__global__ void init_bias(float* __restrict__ C, const float* __restrict__ bias)
{
  C[(long long)blockIdx.x * 256 + threadIdx.x] = bias[threadIdx.x];
}

__global__ void rp2_kernel(const float* __restrict__ x, const float* __restrict__ w,
                           const float* __restrict__ bias, float* __restrict__ out)
{
  __shared__ float red[4];
  int b = blockIdx.x, tid = threadIdx.x;
  float p = x[b * 256 + tid] * w[tid];
#pragma unroll
  for (int o = 32; o > 0; o >>= 1) p += __shfl_down(p, o, 64);
  if ((tid & 63) == 0) red[tid >> 6] = p;
  __syncthreads();
  if (tid == 0) out[b] = red[0] + red[1] + red[2] + red[3] + bias[0];
}

// =========================== host launch ===========================
static inline void gemm(hipStream_t s, const float* A, const float* B, float* C,
                        int M, int N, int K, int shift, const float* bias,
                        const float* res, int flags, int splitz = 1)
{
  dim3 g((N + 63) / 64, (M + 63) / 64, splitz);
  gemm_f32<<<g, dim3(256), 0, s>>>(A, B, C, M, N, K, shift, bias, res, flags);
}

extern "C" void kernel_launch(void* const* d_in, const int* in_sizes, int n_in,
                              void* d_out, int out_size, void* d_ws, size_t ws_size,
                              hipStream_t stream)
{
  const float* x_enc  = (const float*)d_in[0];
  const float* conv1_w= (const float*)d_in[1];
  const float* conv1_b= (const float*)d_in[2];
  const float* conv2_w= (const float*)d_in[3];
  const float* conv2_b= (const float*)d_in[4];
  const float* cnn_g  = (const float*)d_in[5];
  const float* cnn_b  = (const float*)d_in[6];
  const float* proj_w = (const float*)d_in[7];
  const float* proj_b = (const float*)d_in[8];
  const float* pln_g  = (const float*)d_in[9];
  const float* pln_b  = (const float*)d_in[10];
  const float* Wq     = (const float*)d_in[11];
  const float* bq     = (const float*)d_in[12];
  const float* Wk     = (const float*)d_in[13];
  const float* bk     = (const float*)d_in[14];
  const float* Wv     = (const float*)d_in[15];
  const float* bv     = (const float*)d_in[16];
  const float* Wo     = (const float*)d_in[17];
  const float* bo     = (const float*)d_in[18];
  const float* Wff1   = (const float*)d_in[19];
  const float* Wff2   = (const float*)d_in[20];
  const float* rp1_w  = (const float*)d_in[21];
  const float* rp1_b  = (const float*)d_in[22];
  const float* rln_g  = (const float*)d_in[23];
  const float* rln_b  = (const float*)d_in[24];
  const float* rp2_w  = (const float*)d_in[25];
  const float* rp2_b  = (const float*)d_in[26];
  (void)in_sizes; (void)n_in;

  const size_t BLD = 64ull * 1024 * 256;
  size_t need;
  {
    size_t o = 3 * BLD
             + 98304 + 131072 + 131072 + 262144 + 262144
             + 65536 + 512 + 1024
             + 1048576 + 1280 + 1280 + 16384 + 49152 + 16384 + 16384;
    need = o * sizeof(float);
  }
  if (ws_size < need) {
    hipMemsetAsync(d_out, 0, (size_t)out_size * sizeof(float), stream);
    return;
  }

  float* ws = (float*)d_ws;
  size_t off = 0;
  auto alloc = [&](size_t n) { float* p = ws + off; off += n; return p; };
  float* BUF0 = alloc(BLD);   // conv1(bf16)/QT(lo half)/agg(bf16)/xd(bf16); WVO scratch
  float* BUF1 = alloc(BLD);   // conv2(bf16)/QT(hi half)/x(bf16)/ffn out(bf16)
  float* BUF2 = alloc(BLD);   // enc(bf16, first half) + Rpart (second half)
  short* CB2Tb = (short*)alloc(98304);
  short* QKTH  = (short*)alloc(131072);
  short* QKTL  = (short*)alloc(131072);
  short* WFF1b = (short*)alloc(262144);
  short* WFF2b = (short*)alloc(262144);
  short* WVOTb = (short*)alloc(65536);
  float* BVO  = alloc(512);
  float* BQK  = alloc(1024);
  float* MV16 = alloc(1048576);   // reused: MV = mean_value[64][1024] (first 64K)
  float* WTS  = alloc(1280);
  int*   DLY  = (int*)alloc(1280);
  float* PE   = alloc(16384);
  float* FIN  = alloc(49152);
  float* O1   = alloc(16384);
  float* O2   = alloc(16384);
  float* WVO  = BUF0;             // scratch, dead before conv1 writes BUF0
  short* ENC  = (short*)BUF2;
  float* QT   = BUF0;             // spans BUF0+BUF1 contiguously: 64*512*1024 fp32
  float* RP   = BUF2 + 8388608;   // 16 groups x 64 b x 2048 partials (free half of BUF2)
  float* MV   = MV16;             // mean_value[64][1024]

  const int M = 65536;
  dim3 blk(256);

  prep_weights<<<1024, blk, 0, stream>>>(conv2_w, Wq, Wk, Wff1, Wff2, bq, bk,
                                         CB2Tb, QKTH, QKTL, WFF1b, WFF2b, BQK);
  for (int i = 0; i < 2; i++)
    gemm(stream, Wv + (size_t)i * 65536, Wo + (size_t)i * 65536,
         WVO + (size_t)i * 65536, 256, 256, 256, 0, nullptr, nullptr, 0);
  vo_finish<<<516, blk, 0, stream>>>(WVO, Wo, bv, bo, WVOTb, BVO);

  // --- CNN frontend (conv2 out bf16) ---
  conv1_direct<<<dim3(16, 64), blk, 0, stream>>>(x_enc, conv1_w, conv1_b, (short*)BUF0);
  gemm_btn<2><<<dim3(512, 1), blk, 0, stream>>>(
      BUF0, CB2Tb, BUF1, nullptr, conv2_b, M, 256, 768, 256,
      FLAG_ABF16 | FLAG_RELU | FLAG_OBF16, 1);
  fixup_conv_b<<<128, blk, 0, stream>>>((short*)BUF1, (const short*)BUF0,
                                        conv2_w, conv2_b);
  ln_rows4bb<<<16384, blk, 0, stream>>>((const short*)BUF1, ENC, cnn_g, cnn_b);

  // --- encoder layers (enc bf16 in BUF2) ---
  for (int i = 0; i < 2; i++) {
    // q,k (fp32, transposed [b][c][t]) -> FFT cross-correlation -> mean_value
    gemm_qkT<<<dim3(512, 4), blk, 0, stream>>>(
        ENC, QKTH + (size_t)i * 131072, QKTL + (size_t)i * 131072,
        QT, BQK + i * 512, 256);
    fft_cross<<<dim3(1024), blk, 0, stream>>>(QT, RP);
    fft_inv<<<64, blk, 0, stream>>>(RP, MV);
    topk_softmax_wave<<<64, dim3(64), 0, stream>>>(MV, WTS, DLY);
    // fused v+o: x = enc + agg(enc) @ W_vo + b_vo  (x stored bf16)
    agg4b<<<dim3(16384), blk, 0, stream>>>(ENC, WTS, DLY, (short*)BUF0);
    gemm_btn<2><<<dim3(512, 1), blk, 0, stream>>>(
        BUF0, WVOTb + (size_t)i * 65536, BUF1, (const float*)ENC, BVO + i * 256,
        M, 256, 256, 256, FLAG_ABF16 | FLAG_OBF16 | FLAG_RESB16, 0);
    decomp4b<<<16384, blk, 0, stream>>>((const short*)BUF1, (short*)BUF0); // xd bf16
    // FFN: 2 chunks of 32768 rows; hidden bf16 in BUF2 (enc dead); out bf16 BUF1
    for (int c = 0; c < 2; c++) {
      const short* xd = (const short*)BUF0 + (size_t)c * 32768 * 256;
      gemm_btn<2><<<dim3(256, 4), blk, 0, stream>>>(
          xd, WFF1b + (size_t)i * 262144, BUF2, nullptr, nullptr,
          32768, 1024, 256, 256, FLAG_ABF16 | FLAG_GELU | FLAG_OBF16, 0);
      gemm_btn<2><<<dim3(256, 1), blk, 0, stream>>>(
          BUF2, WFF2b + (size_t)i * 262144,
          (short*)BUF1 + (size_t)c * 32768 * 256,
          (const float*)xd, nullptr,
          32768, 256, 1024, 1024, FLAG_ABF16 | FLAG_RESB16 | FLAG_OBF16, 0);
    }
    decomp4bf<<<16384, blk, 0, stream>>>((const short*)BUF1, ENC, FIN, i * 256);
  }

  // --- head (fp32, exact) ---
  init_bias<<<64, blk, 0, stream>>>(PE, proj_b);
  gemm(stream, x_enc, proj_w, PE, 64, 256, 16384, 0, nullptr, nullptr, 0, 32);
  ln_rows4<<<16, blk, 0, stream>>>(PE, FIN, pln_g, pln_b, 1, 768, 512);
  init_bias<<<64, blk, 0, stream>>>(O1, rp1_b);
  gemm(stream, FIN, rp1_w, O1, 64, 256, 768, 0, nullptr, nullptr, 0, 4);
  ln_rows4<<<16, blk, 0, stream>>>(O1, O2, rln_g, rln_b, 1, 256, 0);
  rp2_kernel<<<64, blk, 0, stream>>>(O2, rp2_w, rp2_b, (float*)d_out);
}

// Round 9
// 1398.768 us; speedup vs baseline: 1.8475x; 1.8475x over previous
//
#include <hip/hip_runtime.h>
#include <math.h>

#define FLAG_ACC     1
#define FLAG_RELU    2
#define FLAG_GELU    4
#define FLAG_ABF16   8
#define FLAG_OBF16  16
#define FLAG_RESB16 32

typedef __attribute__((ext_vector_type(8))) short short8;
typedef __attribute__((ext_vector_type(4))) short short4v;
typedef __attribute__((ext_vector_type(4))) float f32x4;

__device__ __forceinline__ short f2bf(float f) {
  unsigned u = __builtin_bit_cast(unsigned, f);
  unsigned r = u + 0x7fffu + ((u >> 16) & 1u);
  return (short)(r >> 16);
}
__device__ __forceinline__ float bf2f(short s) {
  unsigned u = ((unsigned)(unsigned short)s) << 16;
  return __builtin_bit_cast(float, u);
}
__device__ __forceinline__ void load_lds16(const void* g, void* lds) {
  __builtin_amdgcn_global_load_lds(
      (const __attribute__((address_space(1))) void*)g,
      (__attribute__((address_space(3))) void*)lds, 16, 0, 0);
}

// ---------------- generic fp32 tiled GEMM (head + W_vo prep) ----------------
__global__ __launch_bounds__(256) void gemm_f32(
    const float* __restrict__ A, const float* __restrict__ B, float* __restrict__ C,
    int M, int N, int K, int a_shift,
    const float* __restrict__ bias, const float* __restrict__ residual, int flags)
{
  __shared__ float As[16][65];
  __shared__ float Bs[16][64];
  const int tid = threadIdx.x;
  const int tx = tid & 15, ty = tid >> 4;
  const int row0 = blockIdx.y * 64;
  const int col0 = blockIdx.x * 64;
  int kbeg = 0, kend = K;
  if ((int)gridDim.z > 1) {
    int kchunk = ((K + (int)gridDim.z - 1) / (int)gridDim.z + 15) & ~15;
    kbeg = (int)blockIdx.z * kchunk;
    kend = min(K, kbeg + kchunk);
  }
  float acc[4][4] = {};
  const int a_m = tid >> 2;
  const int a_k = (tid & 3) << 2;
  const int b_n = (tid & 15) << 2;
  const int b_k = tid >> 4;
  for (int k0 = kbeg; k0 < kend; k0 += 16) {
    int srow = row0 + a_m + a_shift;
    float4 av = make_float4(0.f, 0.f, 0.f, 0.f);
    if (srow >= 0 && srow < M)
      av = *reinterpret_cast<const float4*>(A + (long long)srow * K + (k0 + a_k));
    As[a_k + 0][a_m] = av.x; As[a_k + 1][a_m] = av.y;
    As[a_k + 2][a_m] = av.z; As[a_k + 3][a_m] = av.w;
    float4 bv = make_float4(0.f, 0.f, 0.f, 0.f);
    int brow = k0 + b_k;
    if (brow < K)
      bv = *reinterpret_cast<const float4*>(B + (long long)brow * N + (col0 + b_n));
    Bs[b_k][b_n + 0] = bv.x; Bs[b_k][b_n + 1] = bv.y;
    Bs[b_k][b_n + 2] = bv.z; Bs[b_k][b_n + 3] = bv.w;
    __syncthreads();
#pragma unroll
    for (int kk = 0; kk < 16; kk++) {
      float ar[4], br[4];
#pragma unroll
      for (int i = 0; i < 4; i++) ar[i] = As[kk][ty * 4 + i];
#pragma unroll
      for (int j = 0; j < 4; j++) br[j] = Bs[kk][tx * 4 + j];
#pragma unroll
      for (int i = 0; i < 4; i++)
#pragma unroll
        for (int j = 0; j < 4; j++)
          acc[i][j] += ar[i] * br[j];
    }
    __syncthreads();
  }
  if ((int)gridDim.z > 1) {
#pragma unroll
    for (int i = 0; i < 4; i++) {
      int r = row0 + ty * 4 + i; if (r >= M) continue;
#pragma unroll
      for (int j = 0; j < 4; j++) {
        int c = col0 + tx * 4 + j; if (c >= N) continue;
        atomicAdd(&C[(long long)r * N + c], acc[i][j]);
      }
    }
    return;
  }
#pragma unroll
  for (int i = 0; i < 4; i++) {
    int r = row0 + ty * 4 + i; if (r >= M) continue;
#pragma unroll
    for (int j = 0; j < 4; j++) {
      int c = col0 + tx * 4 + j; if (c >= N) continue;
      float v = acc[i][j];
      if (bias)     v += bias[c];
      if (residual) v += residual[(long long)r * N + c];
      if (flags & FLAG_ACC)  v += C[(long long)r * N + c];
      if (flags & FLAG_RELU) v = fmaxf(v, 0.f);
      if (flags & FLAG_GELU) v = 0.5f * v * (1.f + erff(v * 0.70710678118654752f));
      C[(long long)r * N + c] = v;
    }
  }
}

// ---------------- bf16 MFMA GEMM, BK=64, 128x128 tile, 8 waves/block ---------------
// R2 single-buffered schedule (measured best), but 512 threads: each wave computes
// a 32x64 sub-tile (acc[2][4] = 32 AGPR, ~60 VGPR). Doubles resident waves/CU
// (8 -> 16) for the latency-bound regime identified in R8 (occupancy-scaling).
__global__ __launch_bounds__(512) void gemm_bt8(
    const void* __restrict__ Av, const short* __restrict__ Btb, void* __restrict__ Cv,
    const float* __restrict__ residual, const float* __restrict__ bias,
    int M, int N, int K, int lda, int flags, int tapped)
{
  __shared__ __align__(16) short Asl[8192];
  __shared__ __align__(16) short Bsl[8192];
  const int tid = threadIdx.x;
  const int row0 = blockIdx.x * 128;
  const int col0 = blockIdx.y * 128;
  const int lane = tid & 63;
  const int wave = tid >> 6;            // 0..7
  const int wm = (wave >> 1) * 32;      // 4 row groups of 32
  const int wn = (wave & 1) * 64;       // 2 col groups of 64
  const int fm = lane & 15;
  const int k8c = lane >> 4;
  const int mr = tid >> 2;              // 0..127 (reg-staged A row)
  const int mkc = tid & 3;              // 2 slots per thread: mkc*2 + j
  const int msw = mr & 7;
  const bool a_dma = (flags & FLAG_ABF16) && !tapped;

  f32x4 acc[2][4] = {};
  for (int k0 = 0; k0 < K; k0 += 64) {
    __syncthreads();
#pragma unroll
    for (int u = 0; u < 2; u++) {       // B via DMA: 16 ops over 8 waves
      int p = (wave * 2 + u) * 64 + lane;
      int r = p >> 3;
      int kc = (p & 7) ^ (r & 7);
      load_lds16(Btb + (long long)(col0 + r) * K + k0 + kc * 8,
                 (char*)Bsl + (wave * 2 + u) * 1024);
    }
    if (a_dma) {
      const short* Ab = (const short*)Av;
#pragma unroll
      for (int u = 0; u < 2; u++) {
        int p = (wave * 2 + u) * 64 + lane;
        int r = p >> 3;
        int kc = (p & 7) ^ (r & 7);
        load_lds16(Ab + (long long)(row0 + r) * lda + k0 + kc * 8,
                   (char*)Asl + (wave * 2 + u) * 1024);
      }
    } else {
      int arow = row0 + mr + (tapped ? (k0 >> 8) - 1 : 0);
      int acol = tapped ? (k0 & 255) : k0;
      bool ok = (arow >= 0 && arow < M);
      if (flags & FLAG_ABF16) {
        const short* ga = (const short*)Av + (long long)arow * lda + acol + mkc * 16;
        short8 z;
#pragma unroll
        for (int u = 0; u < 8; u++) z[u] = 0;
#pragma unroll
        for (int j = 0; j < 2; j++) {
          short8 v = ok ? *(const short8*)(ga + j * 8) : z;
          *(short8*)&Asl[(mr * 8 + ((mkc * 2 + j) ^ msw)) * 8] = v;
        }
      } else {
        const float* ga = (const float*)Av + (long long)arow * lda + acol + mkc * 16;
#pragma unroll
        for (int j = 0; j < 2; j++) {
          float4 f0 = make_float4(0.f,0.f,0.f,0.f), f1 = f0;
          if (ok) { f0 = *(const float4*)(ga + j * 8); f1 = *(const float4*)(ga + j * 8 + 4); }
          short8 v;
          v[0]=f2bf(f0.x); v[1]=f2bf(f0.y); v[2]=f2bf(f0.z); v[3]=f2bf(f0.w);
          v[4]=f2bf(f1.x); v[5]=f2bf(f1.y); v[6]=f2bf(f1.z); v[7]=f2bf(f1.w);
          *(short8*)&Asl[(mr * 8 + ((mkc * 2 + j) ^ msw)) * 8] = v;
        }
      }
    }
    __syncthreads();
#pragma unroll
    for (int kk8 = 0; kk8 < 8; kk8 += 4) {
      short8 af[2], bf[4];
#pragma unroll
      for (int i = 0; i < 2; i++) {
        int r = wm + i * 16 + fm;
        af[i] = *(short8*)&Asl[(r * 8 + ((kk8 + k8c) ^ (r & 7))) * 8];
      }
#pragma unroll
      for (int j = 0; j < 4; j++) {
        int r = wn + j * 16 + fm;
        bf[j] = *(short8*)&Bsl[(r * 8 + ((kk8 + k8c) ^ (r & 7))) * 8];
      }
#pragma unroll
      for (int i = 0; i < 2; i++)
#pragma unroll
        for (int j = 0; j < 4; j++)
          acc[i][j] = __builtin_amdgcn_mfma_f32_16x16x32_bf16(af[i], bf[j], acc[i][j], 0, 0, 0);
    }
  }
#pragma unroll
  for (int i = 0; i < 2; i++) {
    const int mbase = row0 + wm + i * 16 + (lane >> 4) * 4;
#pragma unroll
    for (int j = 0; j < 4; j++) {
      const int n = col0 + wn + j * 16 + fm;
      const float bs = bias ? bias[n] : 0.f;
#pragma unroll
      for (int r = 0; r < 4; r++) {
        long long idx = (long long)(mbase + r) * N + n;
        float v = acc[i][j][r] + bs;
        if (residual) {
          if (flags & FLAG_RESB16) v += bf2f(((const short*)residual)[idx]);
          else                     v += residual[idx];
        }
        if (flags & FLAG_ACC)  v += ((const float*)Cv)[idx];
        if (flags & FLAG_RELU) v = fmaxf(v, 0.f);
        if (flags & FLAG_GELU) v = 0.5f * v * (1.f + erff(v * 0.70710678118654752f));
        if (flags & FLAG_OBF16) ((short*)Cv)[idx] = f2bf(v);
        else                    ((float*)Cv)[idx] = v;
      }
    }
  }
}

// ---------------- q+k GEMM with fp32 TRANSPOSED output QT[b][c][t] -----------------
// A single bf16 (DMA), B pre-split h/l (DMA), 2 MFMAs, epilogue writes QT fp32.
// QT layout: [(b*512 + n) * 1024 + l]   (n<256: q channel, n>=256: k channel)
__global__ __launch_bounds__(256) void gemm_qkT(
    const short* __restrict__ Ab, const short* __restrict__ Bth,
    const short* __restrict__ Btl, float* __restrict__ QT,
    const float* __restrict__ bias, int K)
{
  __shared__ __align__(16) char smem[24576];
  short* Asl = (short*)smem;
  short* Bhi = (short*)(smem + 8192);
  short* Blo = (short*)(smem + 16384);
  const int tid = threadIdx.x;
  const int row0 = blockIdx.x * 128;
  const int col0 = blockIdx.y * 128;
  const int lane = tid & 63;
  const int wave = tid >> 6;
  const int wm = (wave >> 1) * 64;
  const int wn = (wave & 1) * 64;
  const int fm = lane & 15;
  const int k8c = lane >> 4;

  f32x4 acc[4][4] = {};
  for (int k0 = 0; k0 < K; k0 += 32) {
    __syncthreads();
#pragma unroll
    for (int u = 0; u < 2; u++) {
      int p = (wave + u * 4) * 64 + lane;
      int r = p >> 2;
      int kc = (p & 3) ^ ((r >> 1) & 3);
      long long ao = (long long)(row0 + r) * 256 + k0 + kc * 8;
      long long go = (long long)(col0 + r) * K + k0 + kc * 8;
      int lo = (wave + u * 4) * 1024;
      load_lds16(Ab + ao, (char*)Asl + lo);
      load_lds16(Bth + go, (char*)Bhi + lo);
      load_lds16(Btl + go, (char*)Blo + lo);
    }
    __syncthreads();
    short8 af[4], bh[4], bl[4];
#pragma unroll
    for (int i = 0; i < 4; i++) {
      int r = wm + i * 16 + fm;
      af[i] = *(short8*)&Asl[(r * 4 + (k8c ^ ((r >> 1) & 3))) * 8];
    }
#pragma unroll
    for (int j = 0; j < 4; j++) {
      int r = wn + j * 16 + fm;
      int p = (r * 4 + (k8c ^ ((r >> 1) & 3))) * 8;
      bh[j] = *(short8*)&Bhi[p];
      bl[j] = *(short8*)&Blo[p];
    }
#pragma unroll
    for (int i = 0; i < 4; i++)
#pragma unroll
      for (int j = 0; j < 4; j++) {
        acc[i][j] = __builtin_amdgcn_mfma_f32_16x16x32_bf16(af[i], bh[j], acc[i][j], 0, 0, 0);
        acc[i][j] = __builtin_amdgcn_mfma_f32_16x16x32_bf16(af[i], bl[j], acc[i][j], 0, 0, 0);
      }
  }
#pragma unroll
  for (int i = 0; i < 4; i++) {
    const int mbase = row0 + wm + i * 16 + (lane >> 4) * 4;
    const int bb = mbase >> 10;
    const int l  = mbase & 1023;
#pragma unroll
    for (int j = 0; j < 4; j++) {
      const int n = col0 + wn + j * 16 + fm;
      const float bs = bias[n];
      float4 o = make_float4(acc[i][j][0] + bs, acc[i][j][1] + bs,
                             acc[i][j][2] + bs, acc[i][j][3] + bs);
      *(float4*)&QT[((long long)(bb * 512 + n) << 10) + l] = o;
    }
  }
}

// ---------------- FFT-based autocorrelation mean -----------------------------------
#define SKW(i) ((i) + ((i) >> 5))

__device__ __forceinline__ int rev4_10(int f) {
  return ((f & 3) << 8) | (((f >> 2) & 3) << 6) | (((f >> 4) & 3) << 4)
       | (((f >> 6) & 3) << 2) | ((f >> 8) & 3);
}

template<int M, bool INV, int NCH>
__device__ __forceinline__ void fft_stageN(float2 (*__restrict__ buf)[1056],
                                           const float2* __restrict__ tw, int t) {
  constexpr int LOG2M = (M == 256) ? 8 : (M == 64) ? 6 : (M == 16) ? 4 : (M == 4) ? 2 : 0;
  const int j = t & (M - 1);
  const int base = ((t >> LOG2M) << (LOG2M + 2)) | j;
  float2 w = tw[SKW(j << (8 - LOG2M))];
  const float c1 = w.x, s1 = INV ? -w.y : w.y;
  const float c2 = c1 * c1 - s1 * s1, s2 = 2.f * c1 * s1;
  const float c3 = c2 * c1 - s2 * s1, s3 = c2 * s1 + s2 * c1;
#pragma unroll
  for (int ch = 0; ch < NCH; ch++) {
    float2* s = buf[ch];
    float2 a0 = s[SKW(base)];
    float2 b0 = s[SKW(base + M)];
    float2 d0 = s[SKW(base + 2 * M)];
    float2 e0 = s[SKW(base + 3 * M)];
    float t0r = a0.x + d0.x, t0i = a0.y + d0.y;
    float t1r = a0.x - d0.x, t1i = a0.y - d0.y;
    float t2r = b0.x + e0.x, t2i = b0.y + e0.y;
    float t3r = b0.x - e0.x, t3i = b0.y - e0.y;
    float y0r = t0r + t2r, y0i = t0i + t2i;
    float y2r = t0r - t2r, y2i = t0i - t2i;
    float y1r, y1i, y3r, y3i;
    if (!INV) { y1r = t1r + t3i; y1i = t1i - t3r; y3r = t1r - t3i; y3i = t1i + t3r; }
    else      { y1r = t1r - t3i; y1i = t1i + t3r; y3r = t1r + t3i; y3i = t1i - t3r; }
    s[SKW(base)]         = make_float2(y0r, y0i);
    s[SKW(base + M)]     = make_float2(y1r * c1 - y1i * s1, y1r * s1 + y1i * c1);
    s[SKW(base + 2 * M)] = make_float2(y2r * c2 - y2i * s2, y2r * s2 + y2i * c2);
    s[SKW(base + 3 * M)] = make_float2(y3r * c3 - y3i * s3, y3r * s3 + y3i * c3);
  }
}

__global__ __launch_bounds__(256) void fft_cross(
    const float* __restrict__ QT, float* __restrict__ Rpart)
{
  __shared__ float2 buf[4][1056];
  __shared__ float2 tw[264];
  const int tid = threadIdx.x;
  const int b = blockIdx.x & 63;
  const int g = blockIdx.x >> 6;
  {
    float s, c;
    sincosf(-1.5707963267948966f * (float)tid * (1.f / 256.f), &s, &c);
    tw[SKW(tid)] = make_float2(c, s);
  }
  const float* Qb = QT + (long long)b * 524288;
  const int c0 = g * 16;
  float4 qv[4], kv[4];
#pragma unroll
  for (int c = 0; c < 4; c++) {
    qv[c] = *(const float4*)(Qb + ((long long)(c0 + c) << 10) + tid * 4);
    kv[c] = *(const float4*)(Qb + ((long long)(256 + c0 + c) << 10) + tid * 4);
  }
  float aR[4] = {0.f, 0.f, 0.f, 0.f}, aI[4] = {0.f, 0.f, 0.f, 0.f};
  __syncthreads();
  for (int q4 = 0; q4 < 4; q4++) {
    const int i0 = tid * 4;
#pragma unroll
    for (int c = 0; c < 4; c++) {
      buf[c][SKW(i0 + 0)] = make_float2(qv[c].x, kv[c].x);
      buf[c][SKW(i0 + 1)] = make_float2(qv[c].y, kv[c].y);
      buf[c][SKW(i0 + 2)] = make_float2(qv[c].z, kv[c].z);
      buf[c][SKW(i0 + 3)] = make_float2(qv[c].w, kv[c].w);
    }
    if (q4 < 3) {
      const int cb = c0 + (q4 + 1) * 4;
#pragma unroll
      for (int c = 0; c < 4; c++) {
        qv[c] = *(const float4*)(Qb + ((long long)(cb + c) << 10) + tid * 4);
        kv[c] = *(const float4*)(Qb + ((long long)(256 + cb + c) << 10) + tid * 4);
      }
    }
    __syncthreads();
    fft_stageN<256, false, 4>(buf, tw, tid); __syncthreads();
    fft_stageN<64,  false, 4>(buf, tw, tid); __syncthreads();
    fft_stageN<16,  false, 4>(buf, tw, tid); __syncthreads();
    fft_stageN<4,   false, 4>(buf, tw, tid); __syncthreads();
    fft_stageN<1,   false, 4>(buf, tw, tid); __syncthreads();
#pragma unroll
    for (int u = 0; u < 4; u++) {
      const int f = tid + (u << 8);
      const int p1 = SKW(rev4_10(f));
      const int p2 = SKW(rev4_10((1024 - f) & 1023));
#pragma unroll
      for (int c = 0; c < 4; c++) {
        float2 z1 = buf[c][p1];
        float2 z2 = buf[c][p2];
        float Qr = 0.5f * (z1.x + z2.x), Qi = 0.5f * (z1.y - z2.y);
        float Kr = 0.5f * (z1.y + z2.y), Ki = 0.5f * (z2.x - z1.x);
        aR[u] += Qr * Kr + Qi * Ki;
        aI[u] += Qi * Kr - Qr * Ki;
      }
    }
    __syncthreads();
  }
  float* Rp = Rpart + (long long)(g * 64 + b) * 2048;
#pragma unroll
  for (int u = 0; u < 4; u++) {
    Rp[tid + (u << 8)] = aR[u];
    Rp[1024 + tid + (u << 8)] = aI[u];
  }
}

__global__ __launch_bounds__(256) void fft_inv(
    const float* __restrict__ Rpart, float* __restrict__ MV)
{
  __shared__ float2 ping[1056], tw[264];
  const int tid = threadIdx.x;
  const int b = blockIdx.x;
  {
    float s, c;
    sincosf(-1.5707963267948966f * (float)tid * (1.f / 256.f), &s, &c);
    tw[SKW(tid)] = make_float2(c, s);
  }
#pragma unroll
  for (int u = 0; u < 4; u++) {
    int f = tid + (u << 8);
    float sr = 0.f, si = 0.f;
#pragma unroll
    for (int g = 0; g < 16; g++) {
      const float* Rp = Rpart + (long long)(g * 64 + b) * 2048;
      sr += Rp[f];
      si += Rp[1024 + f];
    }
    ping[SKW(f)] = make_float2(sr, si);
  }
  __syncthreads();
  float2 (*bp)[1056] = reinterpret_cast<float2 (*)[1056]>(ping);
  fft_stageN<256, true, 1>(bp, tw, tid); __syncthreads();
  fft_stageN<64,  true, 1>(bp, tw, tid); __syncthreads();
  fft_stageN<16,  true, 1>(bp, tw, tid); __syncthreads();
  fft_stageN<4,   true, 1>(bp, tw, tid); __syncthreads();
  fft_stageN<1,   true, 1>(bp, tw, tid); __syncthreads();
  const float sc = 1.f / (1024.f * 256.f);
#pragma unroll
  for (int u = 0; u < 4; u++) {
    int p = tid + (u << 8);
    MV[(long long)b * 1024 + rev4_10(p)] = ping[SKW(p)].x * sc;
  }
}

// ------------- one-shot weight prep -------------
__global__ void prep_weights(
    const float* __restrict__ conv2_w, const float* __restrict__ Wq,
    const float* __restrict__ Wk, const float* __restrict__ Wff1,
    const float* __restrict__ Wff2,
    const float* __restrict__ bq, const float* __restrict__ bk,
    short* __restrict__ CB2Tb, short* __restrict__ QKTH, short* __restrict__ QKTL,
    short* __restrict__ WFF1b, short* __restrict__ WFF2b, float* __restrict__ BQK)
{
  const int total = 196608 + 262144 + 524288 + 524288 + 1024;
  for (int idx = blockIdx.x * 256 + threadIdx.x; idx < total;
       idx += gridDim.x * 256) {
    int t = idx;
    if (t < 196608) {
      int o = t / 768, rem = t % 768, kk = rem >> 8, i = rem & 255;
      CB2Tb[t] = f2bf(conv2_w[(o * 256 + i) * 3 + kk]);
    } else if ((t -= 196608) < 262144) {
      int L = t >> 17, rem = t & 131071, r = rem >> 8, k = rem & 255;
      float val = (r < 256) ? Wq[L * 65536 + k * 256 + r]
                            : Wk[L * 65536 + k * 256 + (r - 256)];
      short h = f2bf(val);
      QKTH[t] = h;
      QKTL[t] = f2bf(val - bf2f(h));
    } else if ((t -= 262144) < 524288) {
      WFF1b[t] = f2bf(Wff1[t]);
    } else if ((t -= 524288) < 524288) {
      WFF2b[t] = f2bf(Wff2[t]);
    } else {
      t -= 524288;
      int L = t >> 9, j = t & 511;
      BQK[t] = (j < 256) ? bq[L * 256 + j] : bk[L * 256 + (j - 256)];
    }
  }
}

// ------------- W_vo finish -------------
__global__ void vo_finish(const float* __restrict__ WVO, const float* __restrict__ Wo,
                          const float* __restrict__ bv, const float* __restrict__ bo,
                          short* __restrict__ WVOTb, float* __restrict__ BVO)
{
  const int total = 131072 + 512;
  for (int idx = blockIdx.x * 256 + threadIdx.x; idx < total;
       idx += gridDim.x * 256) {
    if (idx < 131072) {
      int L = idx >> 16, rem = idx & 65535, n = rem >> 8, k = rem & 255;
      WVOTb[idx] = f2bf(WVO[L * 65536 + k * 256 + n]);
    } else {
      int j = idx - 131072;
      int L = j >> 8, n = j & 255;
      float acc = bo[L * 256 + n];
      for (int k = 0; k < 256; k++)
        acc += bv[L * 256 + k] * Wo[(long long)L * 65536 + k * 256 + n];
      BVO[j] = acc;
    }
  }
}

// ------------- conv1 direct -> bf16 out -------------
__global__ __launch_bounds__(256) void conv1_direct(
    const float* __restrict__ x, const float* __restrict__ w,
    const float* __restrict__ bias, short* __restrict__ out)
{
  __shared__ float xs[66][16];
  const int b = blockIdx.y, lg = blockIdx.x, tid = threadIdx.x;
  const int l0 = lg * 64;
  for (int idx = tid; idx < 1056; idx += 256) {
    int r = idx >> 4, c = idx & 15;
    int l = l0 + r - 1;
    xs[r][c] = (l >= 0 && l < 1024) ? x[((long long)b * 1024 + l) * 16 + c] : 0.f;
  }
  float wr[48];
#pragma unroll
  for (int u = 0; u < 48; u++) wr[u] = w[tid * 48 + u];
  const float bs = bias[tid];
  __syncthreads();
  for (int r = 0; r < 64; r++) {
    float acc = bs;
#pragma unroll
    for (int i = 0; i < 16; i++) {
      acc += xs[r + 0][i] * wr[i * 3 + 0];
      acc += xs[r + 1][i] * wr[i * 3 + 1];
      acc += xs[r + 2][i] * wr[i * 3 + 2];
    }
    out[((long long)b * 1024 + l0 + r) * 256 + tid] = f2bf(fmaxf(acc, 0.f));
  }
}

// ------------- conv2 batch-edge fixup (bf16 src rows, bf16 out) -------------
__global__ void fixup_conv_b(short* __restrict__ h, const short* __restrict__ src,
                             const float* __restrict__ w, const float* __restrict__ bias)
{
  int b = blockIdx.x >> 1;
  int l = (blockIdx.x & 1) ? 1023 : 0;
  int o = threadIdx.x;
  float acc = bias[o];
  for (int kk = 0; kk < 3; kk++) {
    int t = l + kk - 1;
    if (t < 0 || t > 1023) continue;
    const short* srow = src + ((long long)b * 1024 + t) * 256;
    const float* wrow = w + (long long)o * 256 * 3 + kk;
    for (int i = 0; i < 256; i++) acc += bf2f(srow[i]) * wrow[(long long)i * 3];
  }
  h[((long long)b * 1024 + l) * 256 + o] = f2bf(fmaxf(acc, 0.f));
}

// ------------- LayerNorm fp32 out (head path) -------------
__global__ __launch_bounds__(256) void ln_rows4(
    const float* __restrict__ in, float* __restrict__ out,
    const float* __restrict__ g, const float* __restrict__ b,
    int prerelu, int out_stride, int out_off)
{
  const int row = blockIdx.x * 4 + (threadIdx.x >> 6);
  const int lane = threadIdx.x & 63;
  float4 x = ((const float4*)(in + (long long)row * 256))[lane];
  if (prerelu) {
    x.x = fmaxf(x.x, 0.f); x.y = fmaxf(x.y, 0.f);
    x.z = fmaxf(x.z, 0.f); x.w = fmaxf(x.w, 0.f);
  }
  float s = x.x + x.y + x.z + x.w;
#pragma unroll
  for (int o = 32; o > 0; o >>= 1) s += __shfl_xor(s, o, 64);
  float mean = s * (1.f / 256.f);
  float4 d = make_float4(x.x - mean, x.y - mean, x.z - mean, x.w - mean);
  float s2 = d.x * d.x + d.y * d.y + d.z * d.z + d.w * d.w;
#pragma unroll
  for (int o = 32; o > 0; o >>= 1) s2 += __shfl_xor(s2, o, 64);
  float rsd = rsqrtf(s2 * (1.f / 256.f) + 1e-5f);
  float4 gg = ((const float4*)g)[lane];
  float4 bb = ((const float4*)b)[lane];
  float4 o4 = make_float4(d.x * rsd * gg.x + bb.x, d.y * rsd * gg.y + bb.y,
                          d.z * rsd * gg.z + bb.z, d.w * rsd * gg.w + bb.w);
  ((float4*)(out + (long long)row * out_stride + out_off))[lane] = o4;
}

// ------------- LayerNorm bf16 in -> bf16 out (enc producer) -------------
__global__ __launch_bounds__(256) void ln_rows4bb(
    const short* __restrict__ in, short* __restrict__ out,
    const float* __restrict__ g, const float* __restrict__ b)
{
  const int row = blockIdx.x * 4 + (threadIdx.x >> 6);
  const int lane = threadIdx.x & 63;
  short4v xb = ((const short4v*)in)[(long long)row * 64 + lane];
  float4 x = make_float4(bf2f(xb[0]), bf2f(xb[1]), bf2f(xb[2]), bf2f(xb[3]));
  float s = x.x + x.y + x.z + x.w;
#pragma unroll
  for (int o = 32; o > 0; o >>= 1) s += __shfl_xor(s, o, 64);
  float mean = s * (1.f / 256.f);
  float4 d = make_float4(x.x - mean, x.y - mean, x.z - mean, x.w - mean);
  float s2 = d.x * d.x + d.y * d.y + d.z * d.z + d.w * d.w;
#pragma unroll
  for (int o = 32; o > 0; o >>= 1) s2 += __shfl_xor(s2, o, 64);
  float rsd = rsqrtf(s2 * (1.f / 256.f) + 1e-5f);
  float4 gg = ((const float4*)g)[lane];
  float4 bb = ((const float4*)b)[lane];
  short4v o4;
  o4[0] = f2bf(d.x * rsd * gg.x + bb.x);
  o4[1] = f2bf(d.y * rsd * gg.y + bb.y);
  o4[2] = f2bf(d.z * rsd * gg.z + bb.z);
  o4[3] = f2bf(d.w * rsd * gg.w + bb.w);
  ((short4v*)out)[(long long)row * 64 + lane] = o4;
}

// ------------- series_decomp bf16 -> bf16 enc (+fp32 FIN pool row), XCD-clustered --
__global__ void decomp4bf(const short* __restrict__ in, short* __restrict__ out,
                          float* __restrict__ fin, int finoff)
{
  const int id = blockIdx.x;
  const int c = id & 7;
  const int s = id >> 3;
  const int b = c + 8 * (s >> 8);
  const int lg = s & 255;
  const int l = lg * 4 + (threadIdx.x >> 6);
  const int c4 = threadIdx.x & 63;
  const short4v* base = (const short4v*)(in + (long long)b * 262144);
  float4 acc = make_float4(0.f, 0.f, 0.f, 0.f);
#pragma unroll
  for (int j = -12; j <= 12; j++) {
    int t = l + j;
    t = t < 0 ? 0 : (t > 1023 ? 1023 : t);
    short4v x = base[t * 64 + c4];
    acc.x += bf2f(x[0]); acc.y += bf2f(x[1]);
    acc.z += bf2f(x[2]); acc.w += bf2f(x[3]);
  }
  short4v x0 = base[l * 64 + c4];
  float4 o = make_float4(bf2f(x0[0]) - acc.x * (1.f / 25.f),
                         bf2f(x0[1]) - acc.y * (1.f / 25.f),
                         bf2f(x0[2]) - acc.z * (1.f / 25.f),
                         bf2f(x0[3]) - acc.w * (1.f / 25.f));
  short4v ob;
  ob[0] = f2bf(o.x); ob[1] = f2bf(o.y); ob[2] = f2bf(o.z); ob[3] = f2bf(o.w);
  ((short4v*)out)[((long long)b * 1024 + l) * 64 + c4] = ob;
  if (l == 1023) {
    float* f = fin + (long long)b * 768 + finoff + c4 * 4;
    f[0] = o.x; f[1] = o.y; f[2] = o.z; f[3] = o.w;
  }
}

// ------------- series_decomp bf16->bf16, XCD-clustered -------------
__global__ void decomp4b(const short* __restrict__ in, short* __restrict__ out)
{
  const int id = blockIdx.x;
  const int c = id & 7;
  const int s = id >> 3;
  const int b = c + 8 * (s >> 8);
  const int lg = s & 255;
  const int l = lg * 4 + (threadIdx.x >> 6);
  const int c4 = threadIdx.x & 63;
  const short4v* base = (const short4v*)(in + (long long)b * 262144);
  float4 acc = make_float4(0.f, 0.f, 0.f, 0.f);
#pragma unroll
  for (int j = -12; j <= 12; j++) {
    int t = l + j;
    t = t < 0 ? 0 : (t > 1023 ? 1023 : t);
    short4v x = base[t * 64 + c4];
    acc.x += bf2f(x[0]); acc.y += bf2f(x[1]);
    acc.z += bf2f(x[2]); acc.w += bf2f(x[3]);
  }
  short4v x0 = base[l * 64 + c4];
  short4v o;
  o[0] = f2bf(bf2f(x0[0]) - acc.x * (1.f / 25.f));
  o[1] = f2bf(bf2f(x0[1]) - acc.y * (1.f / 25.f));
  o[2] = f2bf(bf2f(x0[2]) - acc.z * (1.f / 25.f));
  o[3] = f2bf(bf2f(x0[3]) - acc.w * (1.f / 25.f));
  ((short4v*)(out + (long long)b * 262144))[l * 64 + c4] = o;
}

// ------------- top-20 + softmax, one wave per batch -------------
__global__ __launch_bounds__(64) void topk_softmax_wave(
    const float* __restrict__ mv, float* __restrict__ wts, int* __restrict__ dly)
{
  const int b = blockIdx.x, lane = threadIdx.x;
  float v[16];
#pragma unroll
  for (int j = 0; j < 16; j++)
    v[j] = mv[(long long)b * 1024 + lane + 64 * j];
  float selv = 0.f; int seli = 0;
  for (int it = 0; it < 20; it++) {
    float bv = -1e30f; int bi = 0x7fffffff;
#pragma unroll
    for (int j = 0; j < 16; j++) {
      float x = v[j]; int idx = lane + 64 * j;
      if (x > bv || (x == bv && idx < bi)) { bv = x; bi = idx; }
    }
#pragma unroll
    for (int off = 32; off > 0; off >>= 1) {
      float ov = __shfl_xor(bv, off, 64);
      int   oi = __shfl_xor(bi, off, 64);
      if (ov > bv || (ov == bv && oi < bi)) { bv = ov; bi = oi; }
    }
    if (lane == it) { selv = bv; seli = bi; }
    if ((bi & 63) == lane) v[bi >> 6] = -1e30f;
  }
  const float w0 = __shfl(selv, 0, 64);
  float e = (lane < 20) ? __expf(selv - w0) : 0.f;
  float s = e;
#pragma unroll
  for (int off = 32; off > 0; off >>= 1) s += __shfl_xor(s, off, 64);
  if (lane < 20) {
    wts[b * 20 + lane] = e / s;
    dly[b * 20 + lane] = seli;
  }
}

// ------------- delay aggregation bf16 enc -> bf16 out, XCD-clustered ---------------
__global__ void agg4b(const short* __restrict__ enc, const float* __restrict__ wts,
                      const int* __restrict__ dly, short* __restrict__ out)
{
  const int id = blockIdx.x;
  const int c = id & 7;
  const int s = id >> 3;
  const int b = c + 8 * (s >> 8);
  const int lg = s & 255;
  const int l = lg * 4 + (threadIdx.x >> 6);
  const int c4 = threadIdx.x & 63;
  const short4v* vb = (const short4v*)(enc + (long long)b * 262144);
  float4 acc = make_float4(0.f, 0.f, 0.f, 0.f);
  for (int kk = 0; kk < 20; kk++) {
    int d = dly[b * 20 + kk];
    float w = wts[b * 20 + kk];
    short4v x = vb[((l + d) & 1023) * 64 + c4];
    acc.x += w * bf2f(x[0]); acc.y += w * bf2f(x[1]);
    acc.z += w * bf2f(x[2]); acc.w += w * bf2f(x[3]);
  }
  short4v o;
  o[0] = f2bf(acc.x); o[1] = f2bf(acc.y); o[2] = f2bf(acc.z); o[3] = f2bf(acc.w);
  ((short4v*)(out + (long long)b * 262144))[l * 64 + c4] = o;
}

// ------------- small helpers -------------
__global__ void init_bias(float* __restrict__ C, const float* __restrict__ bias)
{
  C[(long long)blockIdx.x * 256 + threadIdx.x] = bias[threadIdx.x];
}

__global__ void rp2_kernel(const float* __restrict__ x, const float* __restrict__ w,
                           const float* __restrict__ bias, float* __restrict__ out)
{
  __shared__ float red[4];
  int b = blockIdx.x, tid = threadIdx.x;
  float p = x[b * 256 + tid] * w[tid];
#pragma unroll
  for (int o = 32; o > 0; o >>= 1) p += __shfl_down(p, o, 64);
  if ((tid & 63) == 0) red[tid >> 6] = p;
  __syncthreads();
  if (tid == 0) out[b] = red[0] + red[1] + red[2] + red[3] + bias[0];
}

// =========================== host launch ===========================
static inline void gemm(hipStream_t s, const float* A, const float* B, float* C,
                        int M, int N, int K, int shift, const float* bias,
                        const float* res, int flags, int splitz = 1)
{
  dim3 g((N + 63) / 64, (M + 63) / 64, splitz);
  gemm_f32<<<g, dim3(256), 0, s>>>(A, B, C, M, N, K, shift, bias, res, flags);
}

extern "C" void kernel_launch(void* const* d_in, const int* in_sizes, int n_in,
                              void* d_out, int out_size, void* d_ws, size_t ws_size,
                              hipStream_t stream)
{
  const float* x_enc  = (const float*)d_in[0];
  const float* conv1_w= (const float*)d_in[1];
  const float* conv1_b= (const float*)d_in[2];
  const float* conv2_w= (const float*)d_in[3];
  const float* conv2_b= (const float*)d_in[4];
  const float* cnn_g  = (const float*)d_in[5];
  const float* cnn_b  = (const float*)d_in[6];
  const float* proj_w = (const float*)d_in[7];
  const float* proj_b = (const float*)d_in[8];
  const float* pln_g  = (const float*)d_in[9];
  const float* pln_b  = (const float*)d_in[10];
  const float* Wq     = (const float*)d_in[11];
  const float* bq     = (const float*)d_in[12];
  const float* Wk     = (const float*)d_in[13];
  const float* bk     = (const float*)d_in[14];
  const float* Wv     = (const float*)d_in[15];
  const float* bv     = (const float*)d_in[16];
  const float* Wo     = (const float*)d_in[17];
  const float* bo     = (const float*)d_in[18];
  const float* Wff1   = (const float*)d_in[19];
  const float* Wff2   = (const float*)d_in[20];
  const float* rp1_w  = (const float*)d_in[21];
  const float* rp1_b  = (const float*)d_in[22];
  const float* rln_g  = (const float*)d_in[23];
  const float* rln_b  = (const float*)d_in[24];
  const float* rp2_w  = (const float*)d_in[25];
  const float* rp2_b  = (const float*)d_in[26];
  (void)in_sizes; (void)n_in;

  const size_t BLD = 64ull * 1024 * 256;
  size_t need;
  {
    size_t o = 3 * BLD
             + 98304 + 131072 + 131072 + 262144 + 262144
             + 65536 + 512 + 1024
             + 1048576 + 1280 + 1280 + 16384 + 49152 + 16384 + 16384;
    need = o * sizeof(float);
  }
  if (ws_size < need) {
    hipMemsetAsync(d_out, 0, (size_t)out_size * sizeof(float), stream);
    return;
  }

  float* ws = (float*)d_ws;
  size_t off = 0;
  auto alloc = [&](size_t n) { float* p = ws + off; off += n; return p; };
  float* BUF0 = alloc(BLD);   // conv1(bf16)/QT(lo half)/agg(bf16)/xd(bf16); WVO scratch
  float* BUF1 = alloc(BLD);   // conv2(bf16)/QT(hi half)/x(bf16)/ffn out(bf16)
  float* BUF2 = alloc(BLD);   // enc(bf16, first half) + Rpart (second half)
  short* CB2Tb = (short*)alloc(98304);
  short* QKTH  = (short*)alloc(131072);
  short* QKTL  = (short*)alloc(131072);
  short* WFF1b = (short*)alloc(262144);
  short* WFF2b = (short*)alloc(262144);
  short* WVOTb = (short*)alloc(65536);
  float* BVO  = alloc(512);
  float* BQK  = alloc(1024);
  float* MV16 = alloc(1048576);   // reused: MV = mean_value[64][1024] (first 64K)
  float* WTS  = alloc(1280);
  int*   DLY  = (int*)alloc(1280);
  float* PE   = alloc(16384);
  float* FIN  = alloc(49152);
  float* O1   = alloc(16384);
  float* O2   = alloc(16384);
  float* WVO  = BUF0;             // scratch, dead before conv1 writes BUF0
  short* ENC  = (short*)BUF2;
  float* QT   = BUF0;             // spans BUF0+BUF1 contiguously: 64*512*1024 fp32
  float* RP   = BUF2 + 8388608;   // 16 groups x 64 b x 2048 partials (free half of BUF2)
  float* MV   = MV16;             // mean_value[64][1024]

  const int M = 65536;
  dim3 blk(256);
  dim3 blk8(512);

  prep_weights<<<1024, blk, 0, stream>>>(conv2_w, Wq, Wk, Wff1, Wff2, bq, bk,
                                         CB2Tb, QKTH, QKTL, WFF1b, WFF2b, BQK);
  for (int i = 0; i < 2; i++)
    gemm(stream, Wv + (size_t)i * 65536, Wo + (size_t)i * 65536,
         WVO + (size_t)i * 65536, 256, 256, 256, 0, nullptr, nullptr, 0);
  vo_finish<<<516, blk, 0, stream>>>(WVO, Wo, bv, bo, WVOTb, BVO);

  // --- CNN frontend (conv2 out bf16) ---
  conv1_direct<<<dim3(16, 64), blk, 0, stream>>>(x_enc, conv1_w, conv1_b, (short*)BUF0);
  gemm_bt8<<<dim3(512, 2), blk8, 0, stream>>>(
      BUF0, CB2Tb, BUF1, nullptr, conv2_b, M, 256, 768, 256,
      FLAG_ABF16 | FLAG_RELU | FLAG_OBF16, 1);
  fixup_conv_b<<<128, blk, 0, stream>>>((short*)BUF1, (const short*)BUF0,
                                        conv2_w, conv2_b);
  ln_rows4bb<<<16384, blk, 0, stream>>>((const short*)BUF1, ENC, cnn_g, cnn_b);

  // --- encoder layers (enc bf16 in BUF2) ---
  for (int i = 0; i < 2; i++) {
    // q,k (fp32, transposed [b][c][t]) -> FFT cross-correlation -> mean_value
    gemm_qkT<<<dim3(512, 4), blk, 0, stream>>>(
        ENC, QKTH + (size_t)i * 131072, QKTL + (size_t)i * 131072,
        QT, BQK + i * 512, 256);
    fft_cross<<<dim3(1024), blk, 0, stream>>>(QT, RP);
    fft_inv<<<64, blk, 0, stream>>>(RP, MV);
    topk_softmax_wave<<<64, dim3(64), 0, stream>>>(MV, WTS, DLY);
    // fused v+o: x = enc + agg(enc) @ W_vo + b_vo  (x stored bf16)
    agg4b<<<dim3(16384), blk, 0, stream>>>(ENC, WTS, DLY, (short*)BUF0);
    gemm_bt8<<<dim3(512, 2), blk8, 0, stream>>>(
        BUF0, WVOTb + (size_t)i * 65536, BUF1, (const float*)ENC, BVO + i * 256,
        M, 256, 256, 256, FLAG_ABF16 | FLAG_OBF16 | FLAG_RESB16, 0);
    decomp4b<<<16384, blk, 0, stream>>>((const short*)BUF1, (short*)BUF0); // xd bf16
    // FFN: 2 chunks of 32768 rows; hidden bf16 in BUF2 (enc dead); out bf16 BUF1
    for (int c = 0; c < 2; c++) {
      const short* xd = (const short*)BUF0 + (size_t)c * 32768 * 256;
      gemm_bt8<<<dim3(256, 8), blk8, 0, stream>>>(
          xd, WFF1b + (size_t)i * 262144, BUF2, nullptr, nullptr,
          32768, 1024, 256, 256, FLAG_ABF16 | FLAG_GELU | FLAG_OBF16, 0);
      gemm_bt8<<<dim3(256, 2), blk8, 0, stream>>>(
          BUF2, WFF2b + (size_t)i * 262144,
          (short*)BUF1 + (size_t)c * 32768 * 256,
          (const float*)xd, nullptr,
          32768, 256, 1024, 1024, FLAG_ABF16 | FLAG_RESB16 | FLAG_OBF16, 0);
    }
    decomp4bf<<<16384, blk, 0, stream>>>((const short*)BUF1, ENC, FIN, i * 256);
  }

  // --- head (fp32, exact) ---
  init_bias<<<64, blk, 0, stream>>>(PE, proj_b);
  gemm(stream, x_enc, proj_w, PE, 64, 256, 16384, 0, nullptr, nullptr, 0, 32);
  ln_rows4<<<16, blk, 0, stream>>>(PE, FIN, pln_g, pln_b, 1, 768, 512);
  init_bias<<<64, blk, 0, stream>>>(O1, rp1_b);
  gemm(stream, FIN, rp1_w, O1, 64, 256, 768, 0, nullptr, nullptr, 0, 4);
  ln_rows4<<<16, blk, 0, stream>>>(O1, O2, rln_g, rln_b, 1, 256, 0);
  rp2_kernel<<<64, blk, 0, stream>>>(O2, rp2_w, rp2_b, (float*)d_out);
}

// Round 10
// 1278.111 us; speedup vs baseline: 2.0219x; 1.0944x over previous
//
#include <hip/hip_runtime.h>
#include <math.h>

#define FLAG_ACC     1
#define FLAG_RELU    2
#define FLAG_GELU    4
#define FLAG_ABF16   8
#define FLAG_OBF16  16
#define FLAG_RESB16 32

typedef __attribute__((ext_vector_type(8))) short short8;
typedef __attribute__((ext_vector_type(4))) short short4v;
typedef __attribute__((ext_vector_type(4))) float f32x4;

__device__ __forceinline__ short f2bf(float f) {
  unsigned u = __builtin_bit_cast(unsigned, f);
  unsigned r = u + 0x7fffu + ((u >> 16) & 1u);
  return (short)(r >> 16);
}
__device__ __forceinline__ float bf2f(short s) {
  unsigned u = ((unsigned)(unsigned short)s) << 16;
  return __builtin_bit_cast(float, u);
}
__device__ __forceinline__ void load_lds16(const void* g, void* lds) {
  __builtin_amdgcn_global_load_lds(
      (const __attribute__((address_space(1))) void*)g,
      (__attribute__((address_space(3))) void*)lds, 16, 0, 0);
}

// ---------------- generic fp32 tiled GEMM (head + W_vo prep) ----------------
__global__ __launch_bounds__(256) void gemm_f32(
    const float* __restrict__ A, const float* __restrict__ B, float* __restrict__ C,
    int M, int N, int K, int a_shift,
    const float* __restrict__ bias, const float* __restrict__ residual, int flags)
{
  __shared__ float As[16][65];
  __shared__ float Bs[16][64];
  const int tid = threadIdx.x;
  const int tx = tid & 15, ty = tid >> 4;
  const int row0 = blockIdx.y * 64;
  const int col0 = blockIdx.x * 64;
  int kbeg = 0, kend = K;
  if ((int)gridDim.z > 1) {
    int kchunk = ((K + (int)gridDim.z - 1) / (int)gridDim.z + 15) & ~15;
    kbeg = (int)blockIdx.z * kchunk;
    kend = min(K, kbeg + kchunk);
  }
  float acc[4][4] = {};
  const int a_m = tid >> 2;
  const int a_k = (tid & 3) << 2;
  const int b_n = (tid & 15) << 2;
  const int b_k = tid >> 4;
  for (int k0 = kbeg; k0 < kend; k0 += 16) {
    int srow = row0 + a_m + a_shift;
    float4 av = make_float4(0.f, 0.f, 0.f, 0.f);
    if (srow >= 0 && srow < M)
      av = *reinterpret_cast<const float4*>(A + (long long)srow * K + (k0 + a_k));
    As[a_k + 0][a_m] = av.x; As[a_k + 1][a_m] = av.y;
    As[a_k + 2][a_m] = av.z; As[a_k + 3][a_m] = av.w;
    float4 bv = make_float4(0.f, 0.f, 0.f, 0.f);
    int brow = k0 + b_k;
    if (brow < K)
      bv = *reinterpret_cast<const float4*>(B + (long long)brow * N + (col0 + b_n));
    Bs[b_k][b_n + 0] = bv.x; Bs[b_k][b_n + 1] = bv.y;
    Bs[b_k][b_n + 2] = bv.z; Bs[b_k][b_n + 3] = bv.w;
    __syncthreads();
#pragma unroll
    for (int kk = 0; kk < 16; kk++) {
      float ar[4], br[4];
#pragma unroll
      for (int i = 0; i < 4; i++) ar[i] = As[kk][ty * 4 + i];
#pragma unroll
      for (int j = 0; j < 4; j++) br[j] = Bs[kk][tx * 4 + j];
#pragma unroll
      for (int i = 0; i < 4; i++)
#pragma unroll
        for (int j = 0; j < 4; j++)
          acc[i][j] += ar[i] * br[j];
    }
    __syncthreads();
  }
  if ((int)gridDim.z > 1) {
#pragma unroll
    for (int i = 0; i < 4; i++) {
      int r = row0 + ty * 4 + i; if (r >= M) continue;
#pragma unroll
      for (int j = 0; j < 4; j++) {
        int c = col0 + tx * 4 + j; if (c >= N) continue;
        atomicAdd(&C[(long long)r * N + c], acc[i][j]);
      }
    }
    return;
  }
#pragma unroll
  for (int i = 0; i < 4; i++) {
    int r = row0 + ty * 4 + i; if (r >= M) continue;
#pragma unroll
    for (int j = 0; j < 4; j++) {
      int c = col0 + tx * 4 + j; if (c >= N) continue;
      float v = acc[i][j];
      if (bias)     v += bias[c];
      if (residual) v += residual[(long long)r * N + c];
      if (flags & FLAG_ACC)  v += C[(long long)r * N + c];
      if (flags & FLAG_RELU) v = fmaxf(v, 0.f);
      if (flags & FLAG_GELU) v = 0.5f * v * (1.f + erff(v * 0.70710678118654752f));
      C[(long long)r * N + c] = v;
    }
  }
}

// ---------------- bf16 MFMA GEMM, BK=64, 128x128 tile, 8 waves/block ---------------
// R2 single-buffered schedule; 512 threads, each wave computes a 32x64 sub-tile
// (acc[2][4] = 32 AGPR). Doubles resident waves/CU vs 4-wave (R9 win: latency-bound).
__global__ __launch_bounds__(512) void gemm_bt8(
    const void* __restrict__ Av, const short* __restrict__ Btb, void* __restrict__ Cv,
    const float* __restrict__ residual, const float* __restrict__ bias,
    int M, int N, int K, int lda, int flags, int tapped)
{
  __shared__ __align__(16) short Asl[8192];
  __shared__ __align__(16) short Bsl[8192];
  const int tid = threadIdx.x;
  const int row0 = blockIdx.x * 128;
  const int col0 = blockIdx.y * 128;
  const int lane = tid & 63;
  const int wave = tid >> 6;            // 0..7
  const int wm = (wave >> 1) * 32;      // 4 row groups of 32
  const int wn = (wave & 1) * 64;       // 2 col groups of 64
  const int fm = lane & 15;
  const int k8c = lane >> 4;
  const int mr = tid >> 2;              // 0..127 (reg-staged A row)
  const int mkc = tid & 3;              // 2 slots per thread: mkc*2 + j
  const int msw = mr & 7;
  const bool a_dma = (flags & FLAG_ABF16) && !tapped;

  f32x4 acc[2][4] = {};
  for (int k0 = 0; k0 < K; k0 += 64) {
    __syncthreads();
#pragma unroll
    for (int u = 0; u < 2; u++) {       // B via DMA: 16 ops over 8 waves
      int p = (wave * 2 + u) * 64 + lane;
      int r = p >> 3;
      int kc = (p & 7) ^ (r & 7);
      load_lds16(Btb + (long long)(col0 + r) * K + k0 + kc * 8,
                 (char*)Bsl + (wave * 2 + u) * 1024);
    }
    if (a_dma) {
      const short* Ab = (const short*)Av;
#pragma unroll
      for (int u = 0; u < 2; u++) {
        int p = (wave * 2 + u) * 64 + lane;
        int r = p >> 3;
        int kc = (p & 7) ^ (r & 7);
        load_lds16(Ab + (long long)(row0 + r) * lda + k0 + kc * 8,
                   (char*)Asl + (wave * 2 + u) * 1024);
      }
    } else {
      int arow = row0 + mr + (tapped ? (k0 >> 8) - 1 : 0);
      int acol = tapped ? (k0 & 255) : k0;
      bool ok = (arow >= 0 && arow < M);
      if (flags & FLAG_ABF16) {
        const short* ga = (const short*)Av + (long long)arow * lda + acol + mkc * 16;
        short8 z;
#pragma unroll
        for (int u = 0; u < 8; u++) z[u] = 0;
#pragma unroll
        for (int j = 0; j < 2; j++) {
          short8 v = ok ? *(const short8*)(ga + j * 8) : z;
          *(short8*)&Asl[(mr * 8 + ((mkc * 2 + j) ^ msw)) * 8] = v;
        }
      } else {
        const float* ga = (const float*)Av + (long long)arow * lda + acol + mkc * 16;
#pragma unroll
        for (int j = 0; j < 2; j++) {
          float4 f0 = make_float4(0.f,0.f,0.f,0.f), f1 = f0;
          if (ok) { f0 = *(const float4*)(ga + j * 8); f1 = *(const float4*)(ga + j * 8 + 4); }
          short8 v;
          v[0]=f2bf(f0.x); v[1]=f2bf(f0.y); v[2]=f2bf(f0.z); v[3]=f2bf(f0.w);
          v[4]=f2bf(f1.x); v[5]=f2bf(f1.y); v[6]=f2bf(f1.z); v[7]=f2bf(f1.w);
          *(short8*)&Asl[(mr * 8 + ((mkc * 2 + j) ^ msw)) * 8] = v;
        }
      }
    }
    __syncthreads();
#pragma unroll
    for (int kk8 = 0; kk8 < 8; kk8 += 4) {
      short8 af[2], bf[4];
#pragma unroll
      for (int i = 0; i < 2; i++) {
        int r = wm + i * 16 + fm;
        af[i] = *(short8*)&Asl[(r * 8 + ((kk8 + k8c) ^ (r & 7))) * 8];
      }
#pragma unroll
      for (int j = 0; j < 4; j++) {
        int r = wn + j * 16 + fm;
        bf[j] = *(short8*)&Bsl[(r * 8 + ((kk8 + k8c) ^ (r & 7))) * 8];
      }
#pragma unroll
      for (int i = 0; i < 2; i++)
#pragma unroll
        for (int j = 0; j < 4; j++)
          acc[i][j] = __builtin_amdgcn_mfma_f32_16x16x32_bf16(af[i], bf[j], acc[i][j], 0, 0, 0);
    }
  }
#pragma unroll
  for (int i = 0; i < 2; i++) {
    const int mbase = row0 + wm + i * 16 + (lane >> 4) * 4;
#pragma unroll
    for (int j = 0; j < 4; j++) {
      const int n = col0 + wn + j * 16 + fm;
      const float bs = bias ? bias[n] : 0.f;
#pragma unroll
      for (int r = 0; r < 4; r++) {
        long long idx = (long long)(mbase + r) * N + n;
        float v = acc[i][j][r] + bs;
        if (residual) {
          if (flags & FLAG_RESB16) v += bf2f(((const short*)residual)[idx]);
          else                     v += residual[idx];
        }
        if (flags & FLAG_ACC)  v += ((const float*)Cv)[idx];
        if (flags & FLAG_RELU) v = fmaxf(v, 0.f);
        if (flags & FLAG_GELU) v = 0.5f * v * (1.f + erff(v * 0.70710678118654752f));
        if (flags & FLAG_OBF16) ((short*)Cv)[idx] = f2bf(v);
        else                    ((float*)Cv)[idx] = v;
      }
    }
  }
}

// ---------------- q+k GEMM with fp32 TRANSPOSED output QT[b][c][t], 8 waves --------
// A single bf16 (DMA), B pre-split h/l (DMA), 2 MFMAs; per-wave 32x64 sub-tile.
// QT layout: [(b*512 + n) * 1024 + l]   (n<256: q channel, n>=256: k channel)
__global__ __launch_bounds__(512) void gemm_qkT(
    const short* __restrict__ Ab, const short* __restrict__ Bth,
    const short* __restrict__ Btl, float* __restrict__ QT,
    const float* __restrict__ bias, int K)
{
  __shared__ __align__(16) char smem[24576];
  short* Asl = (short*)smem;
  short* Bhi = (short*)(smem + 8192);
  short* Blo = (short*)(smem + 16384);
  const int tid = threadIdx.x;
  const int row0 = blockIdx.x * 128;
  const int col0 = blockIdx.y * 128;
  const int lane = tid & 63;
  const int wave = tid >> 6;            // 0..7
  const int wm = (wave >> 1) * 32;
  const int wn = (wave & 1) * 64;
  const int fm = lane & 15;
  const int k8c = lane >> 4;

  f32x4 acc[2][4] = {};
  for (int k0 = 0; k0 < K; k0 += 32) {
    __syncthreads();
    {                                   // 1 DMA op per wave per buffer (8 ops each)
      int p = wave * 64 + lane;
      int r = p >> 2;
      int kc = (p & 3) ^ ((r >> 1) & 3);
      long long ao = (long long)(row0 + r) * 256 + k0 + kc * 8;
      long long go = (long long)(col0 + r) * K + k0 + kc * 8;
      int lo = wave * 1024;
      load_lds16(Ab + ao, (char*)Asl + lo);
      load_lds16(Bth + go, (char*)Bhi + lo);
      load_lds16(Btl + go, (char*)Blo + lo);
    }
    __syncthreads();
    short8 af[2], bh[4], bl[4];
#pragma unroll
    for (int i = 0; i < 2; i++) {
      int r = wm + i * 16 + fm;
      af[i] = *(short8*)&Asl[(r * 4 + (k8c ^ ((r >> 1) & 3))) * 8];
    }
#pragma unroll
    for (int j = 0; j < 4; j++) {
      int r = wn + j * 16 + fm;
      int p = (r * 4 + (k8c ^ ((r >> 1) & 3))) * 8;
      bh[j] = *(short8*)&Bhi[p];
      bl[j] = *(short8*)&Blo[p];
    }
#pragma unroll
    for (int i = 0; i < 2; i++)
#pragma unroll
      for (int j = 0; j < 4; j++) {
        acc[i][j] = __builtin_amdgcn_mfma_f32_16x16x32_bf16(af[i], bh[j], acc[i][j], 0, 0, 0);
        acc[i][j] = __builtin_amdgcn_mfma_f32_16x16x32_bf16(af[i], bl[j], acc[i][j], 0, 0, 0);
      }
  }
#pragma unroll
  for (int i = 0; i < 2; i++) {
    const int mbase = row0 + wm + i * 16 + (lane >> 4) * 4;
    const int bb = mbase >> 10;
    const int l  = mbase & 1023;
#pragma unroll
    for (int j = 0; j < 4; j++) {
      const int n = col0 + wn + j * 16 + fm;
      const float bs = bias[n];
      float4 o = make_float4(acc[i][j][0] + bs, acc[i][j][1] + bs,
                             acc[i][j][2] + bs, acc[i][j][3] + bs);
      *(float4*)&QT[((long long)(bb * 512 + n) << 10) + l] = o;
    }
  }
}

// ---------------- FFT-based autocorrelation mean -----------------------------------
#define SKW(i) ((i) + ((i) >> 5))

__device__ __forceinline__ int rev4_10(int f) {
  return ((f & 3) << 8) | (((f >> 2) & 3) << 6) | (((f >> 4) & 3) << 4)
       | (((f >> 6) & 3) << 2) | ((f >> 8) & 3);
}

template<int M, bool INV, int NCH>
__device__ __forceinline__ void fft_stageN(float2 (*__restrict__ buf)[1056],
                                           const float2* __restrict__ tw, int t) {
  constexpr int LOG2M = (M == 256) ? 8 : (M == 64) ? 6 : (M == 16) ? 4 : (M == 4) ? 2 : 0;
  const int j = t & (M - 1);
  const int base = ((t >> LOG2M) << (LOG2M + 2)) | j;
  float2 w = tw[SKW(j << (8 - LOG2M))];
  const float c1 = w.x, s1 = INV ? -w.y : w.y;
  const float c2 = c1 * c1 - s1 * s1, s2 = 2.f * c1 * s1;
  const float c3 = c2 * c1 - s2 * s1, s3 = c2 * s1 + s2 * c1;
#pragma unroll
  for (int ch = 0; ch < NCH; ch++) {
    float2* s = buf[ch];
    float2 a0 = s[SKW(base)];
    float2 b0 = s[SKW(base + M)];
    float2 d0 = s[SKW(base + 2 * M)];
    float2 e0 = s[SKW(base + 3 * M)];
    float t0r = a0.x + d0.x, t0i = a0.y + d0.y;
    float t1r = a0.x - d0.x, t1i = a0.y - d0.y;
    float t2r = b0.x + e0.x, t2i = b0.y + e0.y;
    float t3r = b0.x - e0.x, t3i = b0.y - e0.y;
    float y0r = t0r + t2r, y0i = t0i + t2i;
    float y2r = t0r - t2r, y2i = t0i - t2i;
    float y1r, y1i, y3r, y3i;
    if (!INV) { y1r = t1r + t3i; y1i = t1i - t3r; y3r = t1r - t3i; y3i = t1i + t3r; }
    else      { y1r = t1r - t3i; y1i = t1i + t3r; y3r = t1r + t3i; y3i = t1i - t3r; }
    s[SKW(base)]         = make_float2(y0r, y0i);
    s[SKW(base + M)]     = make_float2(y1r * c1 - y1i * s1, y1r * s1 + y1i * c1);
    s[SKW(base + 2 * M)] = make_float2(y2r * c2 - y2i * s2, y2r * s2 + y2i * c2);
    s[SKW(base + 3 * M)] = make_float2(y3r * c3 - y3i * s3, y3r * s3 + y3i * c3);
  }
}

__global__ __launch_bounds__(256) void fft_cross(
    const float* __restrict__ QT, float* __restrict__ Rpart)
{
  __shared__ float2 buf[4][1056];
  __shared__ float2 tw[264];
  const int tid = threadIdx.x;
  const int b = blockIdx.x & 63;
  const int g = blockIdx.x >> 6;
  {
    float s, c;
    sincosf(-1.5707963267948966f * (float)tid * (1.f / 256.f), &s, &c);
    tw[SKW(tid)] = make_float2(c, s);
  }
  const float* Qb = QT + (long long)b * 524288;
  const int c0 = g * 16;
  float4 qv[4], kv[4];
#pragma unroll
  for (int c = 0; c < 4; c++) {
    qv[c] = *(const float4*)(Qb + ((long long)(c0 + c) << 10) + tid * 4);
    kv[c] = *(const float4*)(Qb + ((long long)(256 + c0 + c) << 10) + tid * 4);
  }
  float aR[4] = {0.f, 0.f, 0.f, 0.f}, aI[4] = {0.f, 0.f, 0.f, 0.f};
  __syncthreads();
  for (int q4 = 0; q4 < 4; q4++) {
    const int i0 = tid * 4;
#pragma unroll
    for (int c = 0; c < 4; c++) {
      buf[c][SKW(i0 + 0)] = make_float2(qv[c].x, kv[c].x);
      buf[c][SKW(i0 + 1)] = make_float2(qv[c].y, kv[c].y);
      buf[c][SKW(i0 + 2)] = make_float2(qv[c].z, kv[c].z);
      buf[c][SKW(i0 + 3)] = make_float2(qv[c].w, kv[c].w);
    }
    if (q4 < 3) {
      const int cb = c0 + (q4 + 1) * 4;
#pragma unroll
      for (int c = 0; c < 4; c++) {
        qv[c] = *(const float4*)(Qb + ((long long)(cb + c) << 10) + tid * 4);
        kv[c] = *(const float4*)(Qb + ((long long)(256 + cb + c) << 10) + tid * 4);
      }
    }
    __syncthreads();
    fft_stageN<256, false, 4>(buf, tw, tid); __syncthreads();
    fft_stageN<64,  false, 4>(buf, tw, tid); __syncthreads();
    fft_stageN<16,  false, 4>(buf, tw, tid); __syncthreads();
    fft_stageN<4,   false, 4>(buf, tw, tid); __syncthreads();
    fft_stageN<1,   false, 4>(buf, tw, tid); __syncthreads();
#pragma unroll
    for (int u = 0; u < 4; u++) {
      const int f = tid + (u << 8);
      const int p1 = SKW(rev4_10(f));
      const int p2 = SKW(rev4_10((1024 - f) & 1023));
#pragma unroll
      for (int c = 0; c < 4; c++) {
        float2 z1 = buf[c][p1];
        float2 z2 = buf[c][p2];
        float Qr = 0.5f * (z1.x + z2.x), Qi = 0.5f * (z1.y - z2.y);
        float Kr = 0.5f * (z1.y + z2.y), Ki = 0.5f * (z2.x - z1.x);
        aR[u] += Qr * Kr + Qi * Ki;
        aI[u] += Qi * Kr - Qr * Ki;
      }
    }
    __syncthreads();
  }
  float* Rp = Rpart + (long long)(g * 64 + b) * 2048;
#pragma unroll
  for (int u = 0; u < 4; u++) {
    Rp[tid + (u << 8)] = aR[u];
    Rp[1024 + tid + (u << 8)] = aI[u];
  }
}

__global__ __launch_bounds__(256) void fft_inv(
    const float* __restrict__ Rpart, float* __restrict__ MV)
{
  __shared__ float2 ping[1056], tw[264];
  const int tid = threadIdx.x;
  const int b = blockIdx.x;
  {
    float s, c;
    sincosf(-1.5707963267948966f * (float)tid * (1.f / 256.f), &s, &c);
    tw[SKW(tid)] = make_float2(c, s);
  }
#pragma unroll
  for (int u = 0; u < 4; u++) {
    int f = tid + (u << 8);
    float sr = 0.f, si = 0.f;
#pragma unroll
    for (int g = 0; g < 16; g++) {
      const float* Rp = Rpart + (long long)(g * 64 + b) * 2048;
      sr += Rp[f];
      si += Rp[1024 + f];
    }
    ping[SKW(f)] = make_float2(sr, si);
  }
  __syncthreads();
  float2 (*bp)[1056] = reinterpret_cast<float2 (*)[1056]>(ping);
  fft_stageN<256, true, 1>(bp, tw, tid); __syncthreads();
  fft_stageN<64,  true, 1>(bp, tw, tid); __syncthreads();
  fft_stageN<16,  true, 1>(bp, tw, tid); __syncthreads();
  fft_stageN<4,   true, 1>(bp, tw, tid); __syncthreads();
  fft_stageN<1,   true, 1>(bp, tw, tid); __syncthreads();
  const float sc = 1.f / (1024.f * 256.f);
#pragma unroll
  for (int u = 0; u < 4; u++) {
    int p = tid + (u << 8);
    MV[(long long)b * 1024 + rev4_10(p)] = ping[SKW(p)].x * sc;
  }
}

// ------------- one-shot weight prep -------------
__global__ void prep_weights(
    const float* __restrict__ conv2_w, const float* __restrict__ Wq,
    const float* __restrict__ Wk, const float* __restrict__ Wff1,
    const float* __restrict__ Wff2,
    const float* __restrict__ bq, const float* __restrict__ bk,
    short* __restrict__ CB2Tb, short* __restrict__ QKTH, short* __restrict__ QKTL,
    short* __restrict__ WFF1b, short* __restrict__ WFF2b, float* __restrict__ BQK)
{
  const int total = 196608 + 262144 + 524288 + 524288 + 1024;
  for (int idx = blockIdx.x * 256 + threadIdx.x; idx < total;
       idx += gridDim.x * 256) {
    int t = idx;
    if (t < 196608) {
      int o = t / 768, rem = t % 768, kk = rem >> 8, i = rem & 255;
      CB2Tb[t] = f2bf(conv2_w[(o * 256 + i) * 3 + kk]);
    } else if ((t -= 196608) < 262144) {
      int L = t >> 17, rem = t & 131071, r = rem >> 8, k = rem & 255;
      float val = (r < 256) ? Wq[L * 65536 + k * 256 + r]
                            : Wk[L * 65536 + k * 256 + (r - 256)];
      short h = f2bf(val);
      QKTH[t] = h;
      QKTL[t] = f2bf(val - bf2f(h));
    } else if ((t -= 262144) < 524288) {
      WFF1b[t] = f2bf(Wff1[t]);
    } else if ((t -= 524288) < 524288) {
      WFF2b[t] = f2bf(Wff2[t]);
    } else {
      t -= 524288;
      int L = t >> 9, j = t & 511;
      BQK[t] = (j < 256) ? bq[L * 256 + j] : bk[L * 256 + (j - 256)];
    }
  }
}

// ------------- W_vo finish -------------
__global__ void vo_finish(const float* __restrict__ WVO, const float* __restrict__ Wo,
                          const float* __restrict__ bv, const float* __restrict__ bo,
                          short* __restrict__ WVOTb, float* __restrict__ BVO)
{
  const int total = 131072 + 512;
  for (int idx = blockIdx.x * 256 + threadIdx.x; idx < total;
       idx += gridDim.x * 256) {
    if (idx < 131072) {
      int L = idx >> 16, rem = idx & 65535, n = rem >> 8, k = rem & 255;
      WVOTb[idx] = f2bf(WVO[L * 65536 + k * 256 + n]);
    } else {
      int j = idx - 131072;
      int L = j >> 8, n = j & 255;
      float acc = bo[L * 256 + n];
      for (int k = 0; k < 256; k++)
        acc += bv[L * 256 + k] * Wo[(long long)L * 65536 + k * 256 + n];
      BVO[j] = acc;
    }
  }
}

// ------------- conv1 direct -> bf16 out -------------
__global__ __launch_bounds__(256) void conv1_direct(
    const float* __restrict__ x, const float* __restrict__ w,
    const float* __restrict__ bias, short* __restrict__ out)
{
  __shared__ float xs[66][16];
  const int b = blockIdx.y, lg = blockIdx.x, tid = threadIdx.x;
  const int l0 = lg * 64;
  for (int idx = tid; idx < 1056; idx += 256) {
    int r = idx >> 4, c = idx & 15;
    int l = l0 + r - 1;
    xs[r][c] = (l >= 0 && l < 1024) ? x[((long long)b * 1024 + l) * 16 + c] : 0.f;
  }
  float wr[48];
#pragma unroll
  for (int u = 0; u < 48; u++) wr[u] = w[tid * 48 + u];
  const float bs = bias[tid];
  __syncthreads();
  for (int r = 0; r < 64; r++) {
    float acc = bs;
#pragma unroll
    for (int i = 0; i < 16; i++) {
      acc += xs[r + 0][i] * wr[i * 3 + 0];
      acc += xs[r + 1][i] * wr[i * 3 + 1];
      acc += xs[r + 2][i] * wr[i * 3 + 2];
    }
    out[((long long)b * 1024 + l0 + r) * 256 + tid] = f2bf(fmaxf(acc, 0.f));
  }
}

// ------------- conv2 batch-edge fixup: LDS-staged src + bf16 vector weights --------
// One block per (batch, edge-row); valid taps staged to LDS; weights from CB2Tb
// ([o][kk][256] bf16, L2-resident) read as contiguous short8 per thread.
__global__ __launch_bounds__(256) void fixup_conv_b(
    short* __restrict__ h, const short* __restrict__ src,
    const short* __restrict__ w2b, const float* __restrict__ bias)
{
  __shared__ __align__(16) short srows[512];   // 2 rows x 256 ch
  const int b = blockIdx.x >> 1;
  const int edge = blockIdx.x & 1;
  const int l = edge ? 1023 : 0;
  const int o = threadIdx.x;
  const int t0 = edge ? 1022 : 0;     // first valid tap row
  const int kk0 = edge ? 0 : 1;       // kernel index of tap t0
  if (threadIdx.x < 64) {
    int rr = threadIdx.x >> 5, cc = threadIdx.x & 31;
    ((short8*)srows)[rr * 32 + cc] =
        ((const short8*)(src + ((long long)b * 1024 + t0 + rr) * 256))[cc];
  }
  __syncthreads();
  float acc = bias[o];
  const short* w0 = w2b + o * 768 + kk0 * 256;
  const short* w1 = w0 + 256;
#pragma unroll
  for (int c8 = 0; c8 < 32; c8++) {
    short8 wv0 = *(const short8*)(w0 + c8 * 8);
    short8 wv1 = *(const short8*)(w1 + c8 * 8);
    short8 x0 = ((short8*)srows)[c8];
    short8 x1 = ((short8*)srows)[32 + c8];
#pragma unroll
    for (int j = 0; j < 8; j++)
      acc += bf2f(x0[j]) * bf2f(wv0[j]) + bf2f(x1[j]) * bf2f(wv1[j]);
  }
  h[((long long)b * 1024 + l) * 256 + o] = f2bf(fmaxf(acc, 0.f));
}

// ------------- LayerNorm fp32 out (head path) -------------
__global__ __launch_bounds__(256) void ln_rows4(
    const float* __restrict__ in, float* __restrict__ out,
    const float* __restrict__ g, const float* __restrict__ b,
    int prerelu, int out_stride, int out_off)
{
  const int row = blockIdx.x * 4 + (threadIdx.x >> 6);
  const int lane = threadIdx.x & 63;
  float4 x = ((const float4*)(in + (long long)row * 256))[lane];
  if (prerelu) {
    x.x = fmaxf(x.x, 0.f); x.y = fmaxf(x.y, 0.f);
    x.z = fmaxf(x.z, 0.f); x.w = fmaxf(x.w, 0.f);
  }
  float s = x.x + x.y + x.z + x.w;
#pragma unroll
  for (int o = 32; o > 0; o >>= 1) s += __shfl_xor(s, o, 64);
  float mean = s * (1.f / 256.f);
  float4 d = make_float4(x.x - mean, x.y - mean, x.z - mean, x.w - mean);
  float s2 = d.x * d.x + d.y * d.y + d.z * d.z + d.w * d.w;
#pragma unroll
  for (int o = 32; o > 0; o >>= 1) s2 += __shfl_xor(s2, o, 64);
  float rsd = rsqrtf(s2 * (1.f / 256.f) + 1e-5f);
  float4 gg = ((const float4*)g)[lane];
  float4 bb = ((const float4*)b)[lane];
  float4 o4 = make_float4(d.x * rsd * gg.x + bb.x, d.y * rsd * gg.y + bb.y,
                          d.z * rsd * gg.z + bb.z, d.w * rsd * gg.w + bb.w);
  ((float4*)(out + (long long)row * out_stride + out_off))[lane] = o4;
}

// ------------- LayerNorm bf16 in -> bf16 out (enc producer) -------------
__global__ __launch_bounds__(256) void ln_rows4bb(
    const short* __restrict__ in, short* __restrict__ out,
    const float* __restrict__ g, const float* __restrict__ b)
{
  const int row = blockIdx.x * 4 + (threadIdx.x >> 6);
  const int lane = threadIdx.x & 63;
  short4v xb = ((const short4v*)in)[(long long)row * 64 + lane];
  float4 x = make_float4(bf2f(xb[0]), bf2f(xb[1]), bf2f(xb[2]), bf2f(xb[3]));
  float s = x.x + x.y + x.z + x.w;
#pragma unroll
  for (int o = 32; o > 0; o >>= 1) s += __shfl_xor(s, o, 64);
  float mean = s * (1.f / 256.f);
  float4 d = make_float4(x.x - mean, x.y - mean, x.z - mean, x.w - mean);
  float s2 = d.x * d.x + d.y * d.y + d.z * d.z + d.w * d.w;
#pragma unroll
  for (int o = 32; o > 0; o >>= 1) s2 += __shfl_xor(s2, o, 64);
  float rsd = rsqrtf(s2 * (1.f / 256.f) + 1e-5f);
  float4 gg = ((const float4*)g)[lane];
  float4 bb = ((const float4*)b)[lane];
  short4v o4;
  o4[0] = f2bf(d.x * rsd * gg.x + bb.x);
  o4[1] = f2bf(d.y * rsd * gg.y + bb.y);
  o4[2] = f2bf(d.z * rsd * gg.z + bb.z);
  o4[3] = f2bf(d.w * rsd * gg.w + bb.w);
  ((short4v*)out)[(long long)row * 64 + lane] = o4;
}

// ------------- series_decomp bf16 -> bf16 enc (+fp32 FIN pool row), XCD-clustered --
__global__ void decomp4bf(const short* __restrict__ in, short* __restrict__ out,
                          float* __restrict__ fin, int finoff)
{
  const int id = blockIdx.x;
  const int c = id & 7;
  const int s = id >> 3;
  const int b = c + 8 * (s >> 8);
  const int lg = s & 255;
  const int l = lg * 4 + (threadIdx.x >> 6);
  const int c4 = threadIdx.x & 63;
  const short4v* base = (const short4v*)(in + (long long)b * 262144);
  float4 acc = make_float4(0.f, 0.f, 0.f, 0.f);
#pragma unroll
  for (int j = -12; j <= 12; j++) {
    int t = l + j;
    t = t < 0 ? 0 : (t > 1023 ? 1023 : t);
    short4v x = base[t * 64 + c4];
    acc.x += bf2f(x[0]); acc.y += bf2f(x[1]);
    acc.z += bf2f(x[2]); acc.w += bf2f(x[3]);
  }
  short4v x0 = base[l * 64 + c4];
  float4 o = make_float4(bf2f(x0[0]) - acc.x * (1.f / 25.f),
                         bf2f(x0[1]) - acc.y * (1.f / 25.f),
                         bf2f(x0[2]) - acc.z * (1.f / 25.f),
                         bf2f(x0[3]) - acc.w * (1.f / 25.f));
  short4v ob;
  ob[0] = f2bf(o.x); ob[1] = f2bf(o.y); ob[2] = f2bf(o.z); ob[3] = f2bf(o.w);
  ((short4v*)out)[((long long)b * 1024 + l) * 64 + c4] = ob;
  if (l == 1023) {
    float* f = fin + (long long)b * 768 + finoff + c4 * 4;
    f[0] = o.x; f[1] = o.y; f[2] = o.z; f[3] = o.w;
  }
}

// ------------- series_decomp bf16->bf16, XCD-clustered -------------
__global__ void decomp4b(const short* __restrict__ in, short* __restrict__ out)
{
  const int id = blockIdx.x;
  const int c = id & 7;
  const int s = id >> 3;
  const int b = c + 8 * (s >> 8);
  const int lg = s & 255;
  const int l = lg * 4 + (threadIdx.x >> 6);
  const int c4 = threadIdx.x & 63;
  const short4v* base = (const short4v*)(in + (long long)b * 262144);
  float4 acc = make_float4(0.f, 0.f, 0.f, 0.f);
#pragma unroll
  for (int j = -12; j <= 12; j++) {
    int t = l + j;
    t = t < 0 ? 0 : (t > 1023 ? 1023 : t);
    short4v x = base[t * 64 + c4];
    acc.x += bf2f(x[0]); acc.y += bf2f(x[1]);
    acc.z += bf2f(x[2]); acc.w += bf2f(x[3]);
  }
  short4v x0 = base[l * 64 + c4];
  short4v o;
  o[0] = f2bf(bf2f(x0[0]) - acc.x * (1.f / 25.f));
  o[1] = f2bf(bf2f(x0[1]) - acc.y * (1.f / 25.f));
  o[2] = f2bf(bf2f(x0[2]) - acc.z * (1.f / 25.f));
  o[3] = f2bf(bf2f(x0[3]) - acc.w * (1.f / 25.f));
  ((short4v*)(out + (long long)b * 262144))[l * 64 + c4] = o;
}

// ------------- top-20 + softmax, one wave per batch -------------
__global__ __launch_bounds__(64) void topk_softmax_wave(
    const float* __restrict__ mv, float* __restrict__ wts, int* __restrict__ dly)
{
  const int b = blockIdx.x, lane = threadIdx.x;
  float v[16];
#pragma unroll
  for (int j = 0; j < 16; j++)
    v[j] = mv[(long long)b * 1024 + lane + 64 * j];
  float selv = 0.f; int seli = 0;
  for (int it = 0; it < 20; it++) {
    float bv = -1e30f; int bi = 0x7fffffff;
#pragma unroll
    for (int j = 0; j < 16; j++) {
      float x = v[j]; int idx = lane + 64 * j;
      if (x > bv || (x == bv && idx < bi)) { bv = x; bi = idx; }
    }
#pragma unroll
    for (int off = 32; off > 0; off >>= 1) {
      float ov = __shfl_xor(bv, off, 64);
      int   oi = __shfl_xor(bi, off, 64);
      if (ov > bv || (ov == bv && oi < bi)) { bv = ov; bi = oi; }
    }
    if (lane == it) { selv = bv; seli = bi; }
    if ((bi & 63) == lane) v[bi >> 6] = -1e30f;
  }
  const float w0 = __shfl(selv, 0, 64);
  float e = (lane < 20) ? __expf(selv - w0) : 0.f;
  float s = e;
#pragma unroll
  for (int off = 32; off > 0; off >>= 1) s += __shfl_xor(s, off, 64);
  if (lane < 20) {
    wts[b * 20 + lane] = e / s;
    dly[b * 20 + lane] = seli;
  }
}

// ------------- delay aggregation bf16 enc -> bf16 out, XCD-clustered ---------------
__global__ void agg4b(const short* __restrict__ enc, const float* __restrict__ wts,
                      const int* __restrict__ dly, short* __restrict__ out)
{
  const int id = blockIdx.x;
  const int c = id & 7;
  const int s = id >> 3;
  const int b = c + 8 * (s >> 8);
  const int lg = s & 255;
  const int l = lg * 4 + (threadIdx.x >> 6);
  const int c4 = threadIdx.x & 63;
  const short4v* vb = (const short4v*)(enc + (long long)b * 262144);
  float4 acc = make_float4(0.f, 0.f, 0.f, 0.f);
  for (int kk = 0; kk < 20; kk++) {
    int d = dly[b * 20 + kk];
    float w = wts[b * 20 + kk];
    short4v x = vb[((l + d) & 1023) * 64 + c4];
    acc.x += w * bf2f(x[0]); acc.y += w * bf2f(x[1]);
    acc.z += w * bf2f(x[2]); acc.w += w * bf2f(x[3]);
  }
  short4v o;
  o[0] = f2bf(acc.x); o[1] = f2bf(acc.y); o[2] = f2bf(acc.z); o[3] = f2bf(acc.w);
  ((short4v*)(out + (long long)b * 262144))[l * 64 + c4] = o;
}

// ------------- small helpers -------------
__global__ void init_bias(float* __restrict__ C, const float* __restrict__ bias)
{
  C[(long long)blockIdx.x * 256 + threadIdx.x] = bias[threadIdx.x];
}

__global__ void rp2_kernel(const float* __restrict__ x, const float* __restrict__ w,
                           const float* __restrict__ bias, float* __restrict__ out)
{
  __shared__ float red[4];
  int b = blockIdx.x, tid = threadIdx.x;
  float p = x[b * 256 + tid] * w[tid];
#pragma unroll
  for (int o = 32; o > 0; o >>= 1) p += __shfl_down(p, o, 64);
  if ((tid & 63) == 0) red[tid >> 6] = p;
  __syncthreads();
  if (tid == 0) out[b] = red[0] + red[1] + red[2] + red[3] + bias[0];
}

// =========================== host launch ===========================
static inline void gemm(hipStream_t s, const float* A, const float* B, float* C,
                        int M, int N, int K, int shift, const float* bias,
                        const float* res, int flags, int splitz = 1)
{
  dim3 g((N + 63) / 64, (M + 63) / 64, splitz);
  gemm_f32<<<g, dim3(256), 0, s>>>(A, B, C, M, N, K, shift, bias, res, flags);
}

extern "C" void kernel_launch(void* const* d_in, const int* in_sizes, int n_in,
                              void* d_out, int out_size, void* d_ws, size_t ws_size,
                              hipStream_t stream)
{
  const float* x_enc  = (const float*)d_in[0];
  const float* conv1_w= (const float*)d_in[1];
  const float* conv1_b= (const float*)d_in[2];
  const float* conv2_w= (const float*)d_in[3];
  const float* conv2_b= (const float*)d_in[4];
  const float* cnn_g  = (const float*)d_in[5];
  const float* cnn_b  = (const float*)d_in[6];
  const float* proj_w = (const float*)d_in[7];
  const float* proj_b = (const float*)d_in[8];
  const float* pln_g  = (const float*)d_in[9];
  const float* pln_b  = (const float*)d_in[10];
  const float* Wq     = (const float*)d_in[11];
  const float* bq     = (const float*)d_in[12];
  const float* Wk     = (const float*)d_in[13];
  const float* bk     = (const float*)d_in[14];
  const float* Wv     = (const float*)d_in[15];
  const float* bv     = (const float*)d_in[16];
  const float* Wo     = (const float*)d_in[17];
  const float* bo     = (const float*)d_in[18];
  const float* Wff1   = (const float*)d_in[19];
  const float* Wff2   = (const float*)d_in[20];
  const float* rp1_w  = (const float*)d_in[21];
  const float* rp1_b  = (const float*)d_in[22];
  const float* rln_g  = (const float*)d_in[23];
  const float* rln_b  = (const float*)d_in[24];
  const float* rp2_w  = (const float*)d_in[25];
  const float* rp2_b  = (const float*)d_in[26];
  (void)in_sizes; (void)n_in;

  const size_t BLD = 64ull * 1024 * 256;
  size_t need;
  {
    size_t o = 3 * BLD
             + 98304 + 131072 + 131072 + 262144 + 262144
             + 65536 + 512 + 1024
             + 1048576 + 1280 + 1280 + 16384 + 49152 + 16384 + 16384;
    need = o * sizeof(float);
  }
  if (ws_size < need) {
    hipMemsetAsync(d_out, 0, (size_t)out_size * sizeof(float), stream);
    return;
  }

  float* ws = (float*)d_ws;
  size_t off = 0;
  auto alloc = [&](size_t n) { float* p = ws + off; off += n; return p; };
  float* BUF0 = alloc(BLD);   // conv1(bf16)/QT(lo half)/agg(bf16)/xd(bf16); WVO scratch
  float* BUF1 = alloc(BLD);   // conv2(bf16)/QT(hi half)/x(bf16)/ffn out(bf16)
  float* BUF2 = alloc(BLD);   // enc(bf16, first half) + Rpart (second half)
  short* CB2Tb = (short*)alloc(98304);
  short* QKTH  = (short*)alloc(131072);
  short* QKTL  = (short*)alloc(131072);
  short* WFF1b = (short*)alloc(262144);
  short* WFF2b = (short*)alloc(262144);
  short* WVOTb = (short*)alloc(65536);
  float* BVO  = alloc(512);
  float* BQK  = alloc(1024);
  float* MV16 = alloc(1048576);   // reused: MV = mean_value[64][1024] (first 64K)
  float* WTS  = alloc(1280);
  int*   DLY  = (int*)alloc(1280);
  float* PE   = alloc(16384);
  float* FIN  = alloc(49152);
  float* O1   = alloc(16384);
  float* O2   = alloc(16384);
  float* WVO  = BUF0;             // scratch, dead before conv1 writes BUF0
  short* ENC  = (short*)BUF2;
  float* QT   = BUF0;             // spans BUF0+BUF1 contiguously: 64*512*1024 fp32
  float* RP   = BUF2 + 8388608;   // 16 groups x 64 b x 2048 partials (free half of BUF2)
  float* MV   = MV16;             // mean_value[64][1024]

  const int M = 65536;
  dim3 blk(256);
  dim3 blk8(512);

  prep_weights<<<1024, blk, 0, stream>>>(conv2_w, Wq, Wk, Wff1, Wff2, bq, bk,
                                         CB2Tb, QKTH, QKTL, WFF1b, WFF2b, BQK);
  for (int i = 0; i < 2; i++)
    gemm(stream, Wv + (size_t)i * 65536, Wo + (size_t)i * 65536,
         WVO + (size_t)i * 65536, 256, 256, 256, 0, nullptr, nullptr, 0);
  vo_finish<<<516, blk, 0, stream>>>(WVO, Wo, bv, bo, WVOTb, BVO);

  // --- CNN frontend (conv2 out bf16) ---
  conv1_direct<<<dim3(16, 64), blk, 0, stream>>>(x_enc, conv1_w, conv1_b, (short*)BUF0);
  gemm_bt8<<<dim3(512, 2), blk8, 0, stream>>>(
      BUF0, CB2Tb, BUF1, nullptr, conv2_b, M, 256, 768, 256,
      FLAG_ABF16 | FLAG_RELU | FLAG_OBF16, 1);
  fixup_conv_b<<<128, blk, 0, stream>>>((short*)BUF1, (const short*)BUF0,
                                        CB2Tb, conv2_b);
  ln_rows4bb<<<16384, blk, 0, stream>>>((const short*)BUF1, ENC, cnn_g, cnn_b);

  // --- encoder layers (enc bf16 in BUF2) ---
  for (int i = 0; i < 2; i++) {
    // q,k (fp32, transposed [b][c][t]) -> FFT cross-correlation -> mean_value
    gemm_qkT<<<dim3(512, 4), blk8, 0, stream>>>(
        ENC, QKTH + (size_t)i * 131072, QKTL + (size_t)i * 131072,
        QT, BQK + i * 512, 256);
    fft_cross<<<dim3(1024), blk, 0, stream>>>(QT, RP);
    fft_inv<<<64, blk, 0, stream>>>(RP, MV);
    topk_softmax_wave<<<64, dim3(64), 0, stream>>>(MV, WTS, DLY);
    // fused v+o: x = enc + agg(enc) @ W_vo + b_vo  (x stored bf16)
    agg4b<<<dim3(16384), blk, 0, stream>>>(ENC, WTS, DLY, (short*)BUF0);
    gemm_bt8<<<dim3(512, 2), blk8, 0, stream>>>(
        BUF0, WVOTb + (size_t)i * 65536, BUF1, (const float*)ENC, BVO + i * 256,
        M, 256, 256, 256, FLAG_ABF16 | FLAG_OBF16 | FLAG_RESB16, 0);
    decomp4b<<<16384, blk, 0, stream>>>((const short*)BUF1, (short*)BUF0); // xd bf16
    // FFN: 2 chunks of 32768 rows; hidden bf16 in BUF2 (enc dead); out bf16 BUF1
    for (int c = 0; c < 2; c++) {
      const short* xd = (const short*)BUF0 + (size_t)c * 32768 * 256;
      gemm_bt8<<<dim3(256, 8), blk8, 0, stream>>>(
          xd, WFF1b + (size_t)i * 262144, BUF2, nullptr, nullptr,
          32768, 1024, 256, 256, FLAG_ABF16 | FLAG_GELU | FLAG_OBF16, 0);
      gemm_bt8<<<dim3(256, 2), blk8, 0, stream>>>(
          BUF2, WFF2b + (size_t)i * 262144,
          (short*)BUF1 + (size_t)c * 32768 * 256,
          (const float*)xd, nullptr,
          32768, 256, 1024, 1024, FLAG_ABF16 | FLAG_RESB16 | FLAG_OBF16, 0);
    }
    decomp4bf<<<16384, blk, 0, stream>>>((const short*)BUF1, ENC, FIN, i * 256);
  }

  // --- head (fp32, exact) ---
  init_bias<<<64, blk, 0, stream>>>(PE, proj_b);
  gemm(stream, x_enc, proj_w, PE, 64, 256, 16384, 0, nullptr, nullptr, 0, 32);
  ln_rows4<<<16, blk, 0, stream>>>(PE, FIN, pln_g, pln_b, 1, 768, 512);
  init_bias<<<64, blk, 0, stream>>>(O1, rp1_b);
  gemm(stream, FIN, rp1_w, O1, 64, 256, 768, 0, nullptr, nullptr, 0, 4);
  ln_rows4<<<16, blk, 0, stream>>>(O1, O2, rln_g, rln_b, 1, 256, 0);
  rp2_kernel<<<64, blk, 0, stream>>>(O2, rp2_w, rp2_b, (float*)d_out);
}